// Round 13
// baseline (354.631 us; speedup 1.0000x reference)
//
#include <hip/hip_runtime.h>
#include <math.h>

typedef __attribute__((ext_vector_type(8))) short bf16x8;
typedef __attribute__((ext_vector_type(4))) float f32x4;

static constexpr int B_ = 64, L_ = 1024, D_ = 128, K_ = 256;
static constexpr long BLD_ = (long)B_ * L_ * D_;      // 8,388,608
static constexpr long LD_  = (long)L_ * D_;           // 131,072

__device__ __forceinline__ unsigned short f2b(float f) {
    unsigned int u = __builtin_bit_cast(unsigned int, f);
    u = (u + 0x7fffu + ((u >> 16) & 1u)) >> 16;
    return (unsigned short)u;
}
__device__ __forceinline__ float b2f(unsigned short h) {
    unsigned int u = ((unsigned int)h) << 16;
    return __builtin_bit_cast(float, u);
}

__device__ __forceinline__ void gl16(const unsigned short* g, unsigned short* s) {
    __builtin_amdgcn_global_load_lds(
        (const __attribute__((address_space(1))) unsigned int*)g,
        (__attribute__((address_space(3))) unsigned int*)s, 16, 0, 0);
}

// ---- fused transpose/convert: fp32 [R][C] -> bf16 [C][R] (tr=1) or [R][C] (tr=0) ----
struct TrEnt { const float* src; unsigned short* dst; int R, C, tr, start; };
struct TrTab { TrEnt e[17]; };

__global__ __launch_bounds__(256)
void trk(TrTab tab)
{
    __shared__ unsigned short T[64][72];
    int bid = blockIdx.x;
    int ei = 0;
    #pragma unroll
    for (int i = 1; i < 17; ++i) if (bid >= tab.e[i].start) ei = i;
    TrEnt e = tab.e[ei];
    int tile = bid - e.start;
    int ntR = e.R >> 6, ntC = e.C >> 6;
    int nt = ntR * ntC;
    int bb = tile / nt, tt = tile - bb * nt;
    int ri = tt % ntR, ci = tt / ntR;
    const float* src = e.src + (long)bb * e.R * e.C + (long)(ri * 64) * e.C + ci * 64;
    int t = threadIdx.x;
    if (!e.tr) {
        unsigned short* dstd = e.dst + (long)bb * e.R * e.C + (long)(ri * 64) * e.C + ci * 64;
        int r = t >> 2, cq = t & 3;
        const float* s = src + (long)r * e.C + cq * 16;
        unsigned short tmp[16];
        #pragma unroll
        for (int f = 0; f < 4; ++f) {
            float4 v = *(const float4*)(s + f * 4);
            tmp[f*4+0]=f2b(v.x); tmp[f*4+1]=f2b(v.y); tmp[f*4+2]=f2b(v.z); tmp[f*4+3]=f2b(v.w);
        }
        unsigned short* dp = dstd + (long)r * e.C + cq * 16;
        *(uint4*)&dp[0] = *(uint4*)&tmp[0];
        *(uint4*)&dp[8] = *(uint4*)&tmp[8];
        return;
    }
    unsigned short* dst = e.dst + (long)bb * e.R * e.C + (long)(ci * 64) * e.R + ri * 64;
    {
        int r = t >> 2, cq = t & 3;
        const float* s = src + (long)r * e.C + cq * 16;
        unsigned short tmp[16];
        #pragma unroll
        for (int f = 0; f < 4; ++f) {
            float4 v = *(const float4*)(s + f * 4);
            tmp[f*4+0]=f2b(v.x); tmp[f*4+1]=f2b(v.y); tmp[f*4+2]=f2b(v.z); tmp[f*4+3]=f2b(v.w);
        }
        *(uint4*)&T[r][cq*16]   = *(uint4*)&tmp[0];
        *(uint4*)&T[r][cq*16+8] = *(uint4*)&tmp[8];
    }
    __syncthreads();
    {
        int cr = t >> 2, rq = t & 3;
        unsigned short tmp[16];
        #pragma unroll
        for (int j = 0; j < 16; ++j) tmp[j] = T[rq*16 + j][cr];
        unsigned short* dp = dst + (long)cr * e.R + rq * 16;
        *(uint4*)&dp[0] = *(uint4*)&tmp[0];
        *(uint4*)&dp[8] = *(uint4*)&tmp[8];
    }
}

// ---------------- unified MFMA GEMM ----------------
struct OpDesc {
    const unsigned short* A;
    long aOff0, aOff1, aOff2, sA;
    int lda;
    const unsigned short* B0;
    long bOff0, bOff1, bOff2, sB0;
    const unsigned short* B1;
    long sB1;
    int ldb;
    void* C;
    long sC;
    int ldc;
    const float* E0; const float* E1; const float* E2;
    float* ss;
    int Kd;
};

// LDS chunk swizzle: LDS(row, ch) holds global chunk ch ^ ((row>>1)&3).
// gl16: linear dest; per-lane SOURCE chunk = (l&3)^((l>>3)&3). Read: rc = (kg^((fr>>1)&3))*8.
// EPI: 0 store bf16; 1 tanh(acc/16)->bf16; 2 relu(acc+C_old)->bf16 inplace;
//      3 fp32 out + residual; 4 bias+pool->bf16 + per-block sumsq partial
template<int EPI, int AF32, int TM>
__device__ __forceinline__ void gbody(const OpDesc& d, int bx, int by, int zrem,
                                      unsigned short (*As)[TM][32],
                                      unsigned short (*Bs)[128][32])
{
    const int tid = threadIdx.x;
    const long m0 = (long)bx * TM;
    const int n0 = by * 128;
    const int br = zrem >> 6, bb = zrem & 63;

    long aO = (br == 0 ? d.aOff0 : br == 1 ? d.aOff1 : d.aOff2) + (long)bb * d.sA;
    const unsigned short* A_ = d.A + aO;
    const float* Af = (const float*)d.A;
    const unsigned short* Bp;
    int nB = n0;
    if (d.B1 && n0 >= 128) { Bp = d.B1 + (long)bb * d.sB1; nB = n0 - 128; }
    else { Bp = d.B0 + (br == 0 ? d.bOff0 : br == 1 ? d.bOff1 : d.bOff2) + (long)bb * d.sB0; }

    const int w = tid >> 6, l = tid & 63;
    const int wm = (TM == 128) ? (w >> 1) : 0;
    const int wn = (TM == 128) ? (w & 1) : w;
    const int NJ = (TM == 128) ? 4 : 2;
    const int WS = (TM == 128) ? 64 : 32;
    const int fr = l & 15, kg = l >> 4;

    f32x4 acc[4][4];
    #pragma unroll
    for (int i = 0; i < 4; ++i)
        #pragma unroll
        for (int j = 0; j < 4; ++j)
            acc[i][j] = (f32x4){0.f, 0.f, 0.f, 0.f};

    const int sc8 = ((l & 3) ^ ((l >> 3) & 3)) * 8;   // swizzled source chunk offset
    const int rc  = (kg ^ ((fr >> 1) & 3)) * 8;        // swizzled read col

    auto stage = [&](int buf, int k0) {
        if (AF32) {
            int row = tid >> 1, half = tid & 1;
            const float* s = Af + (long)(m0 + row) * d.lda + k0 + half * 16;
            unsigned short tmp[16];
            #pragma unroll
            for (int f = 0; f < 4; ++f) {
                float4 v = *(const float4*)(s + f * 4);
                tmp[f*4+0]=f2b(v.x); tmp[f*4+1]=f2b(v.y); tmp[f*4+2]=f2b(v.z); tmp[f*4+3]=f2b(v.w);
            }
            int sw = (row >> 1) & 3;
            *(uint4*)&As[buf][row][((2*half    ) ^ sw) * 8] = *(uint4*)&tmp[0];
            *(uint4*)&As[buf][row][((2*half + 1) ^ sw) * 8] = *(uint4*)&tmp[8];
        } else if (TM == 128) {
            const unsigned short* ga = A_ + (m0 + 32*w + (l >> 2)) * (long)d.lda + k0 + sc8;
            gl16(ga,                    &As[buf][32*w][0]);
            gl16(ga + 16*(long)d.lda,   &As[buf][32*w + 16][0]);
        } else {
            const unsigned short* ga = A_ + (m0 + 16*w + (l >> 2)) * (long)d.lda + k0 + sc8;
            gl16(ga, &As[buf][16*w][0]);
        }
        const unsigned short* gb = Bp + (long)(nB + 32*w + (l >> 2)) * d.ldb + k0 + sc8;
        gl16(gb,                  &Bs[buf][32*w][0]);
        gl16(gb + 16*(long)d.ldb, &Bs[buf][32*w + 16][0]);
    };

    auto compute = [&](int cb) {
        bf16x8 af[4], bf[4];
        #pragma unroll
        for (int i = 0; i < 4; ++i) af[i] = *(const bf16x8*)&As[cb][wm*64 + i*16 + fr][rc];
        #pragma unroll
        for (int j = 0; j < NJ; ++j) bf[j] = *(const bf16x8*)&Bs[cb][wn*WS + j*16 + fr][rc];
        #pragma unroll
        for (int i = 0; i < 4; ++i)
            #pragma unroll
            for (int j = 0; j < NJ; ++j)
                acc[i][j] = __builtin_amdgcn_mfma_f32_16x16x32_bf16(af[i], bf[j], acc[i][j], 0, 0, 0);
    };

    const int nt = d.Kd >> 5;
    stage(0, 0);
    __syncthreads();
    for (int t = 0; t < nt; ++t) {
        if (t + 1 < nt) stage((t + 1) & 1, (t + 1) << 5);
        compute(t & 1);
        __syncthreads();
    }

    if (EPI == 4) {
        unsigned short* C = (unsigned short*)d.C;
        float lss = 0.f;
        #pragma unroll
        for (int i = 0; i < 4; ++i)
            #pragma unroll
            for (int j = 0; j < 4; ++j) {
                int cg = n0 + wn*64 + j*16 + fr;
                float bias = d.E0[cg];
                #pragma unroll
                for (int r = 0; r < 4; ++r) {
                    float v = acc[i][j][r] + bias;
                    lss += v * v;
                }
            }
        #pragma unroll
        for (int o = 32; o; o >>= 1) lss += __shfl_xor(lss, o);
        __shared__ float red4[4];
        if (l == 0) red4[w] = lss;
        float* eb = (float*)As;
        #pragma unroll
        for (int cc = 0; cc < 4; ++cc) {
            __syncthreads();
            #pragma unroll
            for (int j = 0; j < 4; ++j) {
                int cg = n0 + wn*64 + j*16 + fr;
                float bias = d.E0[cg];
                #pragma unroll
                for (int r = 0; r < 4; ++r)
                    eb[(wm*16 + kg*4 + r)*128 + wn*64 + j*16 + fr] = acc[cc][j][r] + bias;
            }
            __syncthreads();
            int lr = tid >> 3, pc = tid & 7;
            long gr = m0 + (lr < 16 ? cc*16 + lr : 48 + cc*16 + lr);
            unsigned short pk[8];
            #pragma unroll
            for (int e = 0; e < 8; ++e) {
                float v0 = eb[lr*128 + pc*16 + 2*e];
                float v1 = eb[lr*128 + pc*16 + 2*e + 1];
                pk[e] = f2b(v0 + v1);
            }
            *(uint4*)&C[gr * (long)d.ldc + (n0 >> 1) + pc*8] = *(uint4*)&pk[0];
        }
        if (tid == 0)
            d.ss[bx * 2 + by] = red4[0] + red4[1] + red4[2] + red4[3];
    } else if (TM == 64) {
        float* eb = (float*)As;
        #pragma unroll
        for (int cc = 0; cc < 4; ++cc) {
            __syncthreads();
            #pragma unroll
            for (int j = 0; j < 2; ++j)
                #pragma unroll
                for (int r = 0; r < 4; ++r)
                    eb[(kg*4 + r)*128 + wn*32 + j*16 + fr] = acc[cc][j][r];
            __syncthreads();
            unsigned short* C = (unsigned short*)d.C + (long)zrem * d.sC;
            int colx = (tid & 15) * 8;
            int lr = tid >> 4;
            long gr = m0 + cc*16 + lr;
            long gi = gr * (long)d.ldc + n0 + colx;
            unsigned short ov[8];
            if (EPI == 2) *(uint4*)ov = *(const uint4*)&C[gi];
            unsigned short pk[8];
            #pragma unroll
            for (int e = 0; e < 8; ++e) {
                float v = eb[lr*128 + colx + e];
                if (EPI == 1) v = tanhf(v * 0.0625f);
                if (EPI == 2) v = fmaxf(v + b2f(ov[e]), 0.f);
                pk[e] = f2b(v);
            }
            *(uint4*)&C[gi] = *(uint4*)&pk[0];
        }
    } else {
        float* eb = (float*)As;
        #pragma unroll
        for (int cc = 0; cc < 4; ++cc) {
            __syncthreads();
            #pragma unroll
            for (int j = 0; j < 4; ++j)
                #pragma unroll
                for (int r = 0; r < 4; ++r)
                    eb[(wm*16 + kg*4 + r)*128 + wn*64 + j*16 + fr] = acc[cc][j][r];
            __syncthreads();
            if (EPI == 3) {
                long off = (br == 2) ? 0L : (long)(br + 1) * BLD_;
                float* Co = (float*)d.C + off + (long)bb * LD_;
                const float* Ep = (br == 0 ? d.E0 : br == 1 ? d.E1 : d.E2) + (long)bb * LD_;
                int colx = (tid & 31) * 4;
                #pragma unroll
                for (int p = 0; p < 4; ++p) {
                    int lr = (tid >> 5) + 8 * p;
                    long gr = m0 + (lr < 16 ? cc*16 + lr : 48 + cc*16 + lr);
                    long gi = gr * (long)d.ldc + n0 + colx;
                    float4 v = *(float4*)&eb[lr*128 + colx];
                    float4 e4 = *(const float4*)&Ep[gi];
                    v.x += e4.x; v.y += e4.y; v.z += e4.z; v.w += e4.w;
                    *(float4*)&Co[gi] = v;
                }
            } else {
                unsigned short* C = (unsigned short*)d.C + (long)zrem * d.sC;
                int colx = (tid & 15) * 8;
                #pragma unroll
                for (int p = 0; p < 2; ++p) {
                    int lr = (tid >> 4) + 16 * p;
                    long gr = m0 + (lr < 16 ? cc*16 + lr : 48 + cc*16 + lr);
                    long gi = gr * (long)d.ldc + n0 + colx;
                    unsigned short ov[8];
                    if (EPI == 2) *(uint4*)ov = *(const uint4*)&C[gi];
                    unsigned short pk[8];
                    #pragma unroll
                    for (int e = 0; e < 8; ++e) {
                        float v = eb[lr*128 + colx + e];
                        if (EPI == 1) v = tanhf(v * 0.0625f);
                        if (EPI == 2) v = fmaxf(v + b2f(ov[e]), 0.f);
                        pk[e] = f2b(v);
                    }
                    *(uint4*)&C[gi] = *(uint4*)&pk[0];
                }
            }
        }
    }
}

// SWZ=1: XCD-aware bijective remap (requires nwg % 8 == 0)
template<int EPI0, int EPI1, int AF32, int SWZ, int TM>
__global__ __launch_bounds__(256)
void mg(OpDesc d0, OpDesc d1, int zsplit)
{
    __shared__ __align__(16) unsigned short As[2][TM][32];
    __shared__ __align__(16) unsigned short Bs[2][128][32];
    int bx, by, bz;
    if (SWZ) {
        int nwg = gridDim.x * gridDim.y * gridDim.z;
        int c = blockIdx.x + gridDim.x * (blockIdx.y + gridDim.y * blockIdx.z);
        int lid = (c & 7) * (nwg >> 3) + (c >> 3);
        bx = lid % gridDim.x; lid /= gridDim.x;
        by = lid % gridDim.y; bz = lid / gridDim.y;
    } else {
        bx = blockIdx.x; by = blockIdx.y; bz = blockIdx.z;
    }
    if (bz < zsplit) gbody<EPI0, AF32, TM>(d0, bx, by, bz, As, Bs);
    else             gbody<EPI1, AF32, TM>(d1, bx, by, bz - zsplit, As, Bs);
}

// merged BiAMLP || S2: grid (1, 8, 192+256). z<192 -> S2; z>=192 -> BiAMLP
// BiAMLP decode: zb=z-192, op=zb>>7, mtile=((zb&127)<<2)|(by>>1), ntile=by&1  (bijective)
__global__ __launch_bounds__(256)
void mg2(OpDesc dS2, OpDesc dTxt, OpDesc dAud)
{
    __shared__ __align__(16) unsigned short As[2][128][32];
    __shared__ __align__(16) unsigned short Bs[2][128][32];
    int nwg = gridDim.x * gridDim.y * gridDim.z;
    int c = blockIdx.x + gridDim.x * (blockIdx.y + gridDim.y * blockIdx.z);
    int lid = (c & 7) * (nwg >> 3) + (c >> 3);
    int bx = lid % gridDim.x; lid /= gridDim.x;
    int by = lid % gridDim.y;
    int bz = lid / gridDim.y;
    if (bz < 192) {
        gbody<0, 0, 128>(dS2, bx, by, bz, As, Bs);
    } else {
        int zb = bz - 192;
        int op = zb >> 7;
        int mt = ((zb & 127) << 2) | (by >> 1);
        int nt = by & 1;
        gbody<4, 1, 128>(op ? dAud : dTxt, mt, nt, 0, As, Bs);
    }
}

// z = al*q1 + be*q2 (bf16 in place on q1) + per-(b,lc) column sumsq partials (no atomics)
__global__ __launch_bounds__(256)
void k2z(unsigned short* __restrict__ q1, const unsigned short* __restrict__ q2,
         const float* __restrict__ partial, float* __restrict__ colssP)
{
    int t = threadIdx.x;
    float a = partial[t] + partial[t + 256] + partial[t + 512] + partial[t + 768];
    float bsum = partial[1024 + t] + partial[1280 + t] + partial[1536 + t] + partial[1792 + t];
    #pragma unroll
    for (int o = 32; o; o >>= 1) { a += __shfl_xor(a, o); bsum += __shfl_xor(bsum, o); }
    __shared__ float ra[4], rb[4];
    int wv = t >> 6;
    if ((t & 63) == 0) { ra[wv] = a; rb[wv] = bsum; }
    __syncthreads();
    float n1 = sqrtf(ra[0] + ra[1] + ra[2] + ra[3]);
    float n2 = sqrtf(rb[0] + rb[1] + rb[2] + rb[3]);
    float al = n1 / (n1 + n2), be = n2 / (n1 + n2);

    int b = blockIdx.x, lc = blockIdx.y;
    int d = t & 127, ls = t >> 7;
    long base = ((long)b * L_ + (long)lc * 64) * D_;
    float acc = 0.f;
    for (int ll = ls; ll < 64; ll += 2) {
        long idx = base + (long)ll * D_ + d;
        float zv = al * b2f(q1[idx]) + be * b2f(q2[idx]);
        q1[idx] = f2b(zv);
        acc += zv * zv;
    }
    __shared__ float red[256];
    red[t] = acc;
    __syncthreads();
    if (t < 128)
        colssP[((long)b * 16 + lc) * 128 + d] = red[t] + red[t + 128];
}

// GT[b][d][l] = z[b][l][d] / max(sqrt(sum_lc colssP[b][lc][d]),1e-12)
__global__ __launch_bounds__(256)
void k3nT(const unsigned short* __restrict__ z, const float* __restrict__ colssP,
          unsigned short* __restrict__ GT)
{
    __shared__ unsigned short T[128][136];
    int b = blockIdx.x, lt = blockIdx.y;
    int t = threadIdx.x;
    {
        int r = t >> 1, half = t & 1;
        const unsigned short* src = z + ((long)b * L_ + lt * 128 + r) * D_ + half * 64;
        #pragma unroll
        for (int q = 0; q < 8; ++q)
            *(uint4*)&T[r][half*64 + q*8] = *(const uint4*)(src + q*8);
    }
    __syncthreads();
    {
        int d = t >> 1, lh = t & 1;
        float s = 0.f;
        #pragma unroll
        for (int lc = 0; lc < 16; ++lc)
            s += colssP[((long)b * 16 + lc) * 128 + d];
        float inv = 1.f / fmaxf(sqrtf(s), 1e-12f);
        unsigned short tmp[64];
        #pragma unroll
        for (int j = 0; j < 64; ++j) tmp[j] = f2b(b2f(T[lh*64 + j][d]) * inv);
        unsigned short* dp = GT + ((long)b * D_ + d) * L_ + lt * 128 + lh * 64;
        #pragma unroll
        for (int q = 0; q < 8; ++q) *(uint4*)&dp[q*8] = *(uint4*)&tmp[q*8];
    }
}

extern "C" void kernel_launch(void* const* d_in, const int* in_sizes, int n_in,
                              void* d_out, int out_size, void* d_ws, size_t ws_size,
                              hipStream_t stream)
{
    const float* txt = (const float*)d_in[0];
    const float* aud = (const float*)d_in[1];
    const float* vis = (const float*)d_in[2];
    const float* Wi  = (const float*)d_in[3];
    const float* bi  = (const float*)d_in[4];
    const float* Wq  = (const float*)d_in[5];
    const float* bq  = (const float*)d_in[6];
    const float* Waff[3] = { (const float*)d_in[7], (const float*)d_in[8], (const float*)d_in[9] };
    const float* Wlin[3] = { (const float*)d_in[10], (const float*)d_in[11], (const float*)d_in[12] };
    const float* Wc[3]   = { (const float*)d_in[13], (const float*)d_in[14], (const float*)d_in[15] };
    const float* Wh[3]   = { (const float*)d_in[16], (const float*)d_in[17], (const float*)d_in[18] };

    // ---- workspace (bf16 elems) ----
    unsigned short* w16 = (unsigned short*)d_ws;
    unsigned short* featT = w16;                      // 3*BLD  [aud,vis,txt] x [b][d][l]
    unsigned short* q1b   = featT + 3 * BLD_;         // 8,388,608
    unsigned short* q2b   = q1b + BLD_;               // 8,388,608
    unsigned short* WAb   = q2b + BLD_;               // 3,145,728
    unsigned short* WLTb  = WAb + 3145728;            // 786,432
    unsigned short* WCTb  = WLTb + 786432;            // 196,608
    unsigned short* WHTb  = WCTb + 196608;            // 786,432
    unsigned short* WiTb  = WHTb + 786432;            // 32,768
    unsigned short* WqTb  = WiTb + 32768;             // 32,768
    float* partial = (float*)(WqTb + 32768);          // 2048 block partials
    float* colssP  = partial + 2048;                  // 131,072 partials
    // overlays (q1/q2 dead after k3nT)
    unsigned short* Cm3 = q1b;                        // 6,291,456
    unsigned short* Hb3 = q1b + 6291456;              // 6,291,456
    // d_out scratch (fully overwritten by final GEMM)
    unsigned short* S2all = (unsigned short*)d_out;   // 25,165,824
    unsigned short* GT    = S2all + 3 * BLD_;         // 8,388,608

    // ---- transposes/conversions (merged) ----
    TrTab tab;
    auto setE = [&](int i, const float* s, unsigned short* dst, int R, int C, int tr, int start) {
        tab.e[i].src = s; tab.e[i].dst = dst; tab.e[i].R = R; tab.e[i].C = C;
        tab.e[i].tr = tr; tab.e[i].start = start;
    };
    int st = 0;
    setE(0, aud, featT + 0,        1024, 128, 1, st); st += 2048;
    setE(1, vis, featT + BLD_,     1024, 128, 1, st); st += 2048;
    setE(2, txt, featT + 2 * BLD_, 1024, 128, 1, st); st += 2048;
    setE(3, Wi, WiTb, 128, 256, 1, st); st += 8;
    setE(4, Wq, WqTb, 128, 256, 1, st); st += 8;
    for (int i = 0; i < 3; ++i) { setE(5 + i, Wlin[i], WLTb + (long)i * 262144, 1024, 256, 1, st); st += 64; }
    for (int i = 0; i < 3; ++i) { setE(8 + i, Wc[i],   WCTb + (long)i * 65536,  256, 256, 1, st); st += 16; }
    for (int i = 0; i < 3; ++i) { setE(11 + i, Wh[i],  WHTb + (long)i * 262144, 256, 1024, 1, st); st += 64; }
    for (int i = 0; i < 3; ++i) { setE(14 + i, Waff[i], WAb + (long)i * 1048576, 1024, 1024, 0, st); st += 256; }
    trk<<<st, 256, 0, stream>>>(tab);

    // ---- merged BiAMLP || S2 ----
    OpDesc dS2 = {};
    dS2.A = featT; dS2.aOff0 = 0; dS2.aOff1 = BLD_; dS2.aOff2 = 2 * BLD_;
    dS2.sA = LD_; dS2.lda = 1024;
    dS2.B0 = WAb; dS2.bOff0 = 0; dS2.bOff1 = 1048576; dS2.bOff2 = 2097152;
    dS2.sB0 = 0; dS2.ldb = 1024;
    dS2.C = S2all; dS2.sC = LD_; dS2.ldc = 1024; dS2.Kd = 1024;

    OpDesc dTxt = {}, dAud = {};
    dTxt.A = (const unsigned short*)txt; dTxt.lda = 128;
    dTxt.B0 = WiTb; dTxt.ldb = 128;
    dTxt.C = q1b; dTxt.ldc = 128;
    dTxt.E0 = bi; dTxt.ss = partial; dTxt.Kd = 128;
    dAud = dTxt;
    dAud.A = (const unsigned short*)aud; dAud.B0 = WqTb; dAud.C = q2b;
    dAud.E0 = bq; dAud.ss = partial + 1024;

    mg2<<<dim3(1, 8, 448), 256, 0, stream>>>(dS2, dTxt, dAud);

    k2z<<<dim3(64, 16), 256, 0, stream>>>(q1b, q2b, partial, colssP);
    k3nT<<<dim3(64, 8), 256, 0, stream>>>(q1b, colssP, GT);

    // ---- att (tanh) + U merged: 64-row tiles ----
    OpDesc dAtt = {};
    dAtt.A = S2all; dAtt.aOff0 = 0; dAtt.aOff1 = 64 * LD_; dAtt.aOff2 = 128 * LD_;
    dAtt.sA = LD_; dAtt.lda = 1024;
    dAtt.B0 = featT; dAtt.bOff0 = 0; dAtt.bOff1 = 0; dAtt.bOff2 = 2 * BLD_;  // audT,audT,txtT
    dAtt.sB0 = LD_;
    dAtt.B1 = GT; dAtt.sB1 = LD_; dAtt.ldb = 1024;
    dAtt.C = Cm3; dAtt.sC = 32768; dAtt.ldc = 256; dAtt.Kd = 1024;
    OpDesc dU = {};
    dU.A = featT; dU.aOff0 = 0; dU.aOff1 = BLD_; dU.aOff2 = 2 * BLD_;
    dU.sA = LD_; dU.lda = 1024;
    dU.B0 = WLTb; dU.bOff0 = 0; dU.bOff1 = 262144; dU.bOff2 = 524288;
    dU.sB0 = 0; dU.ldb = 1024;
    dU.C = Hb3; dU.sC = 32768; dU.ldc = 256; dU.Kd = 1024;
    mg<1, 0, 0, 1, 64><<<dim3(2, 2, 384), 256, 0, stream>>>(dAtt, dU, 192);

    // ---- T: Hb = relu(Cm @ WC + Hb): 64-row tiles ----
    OpDesc dT = {};
    dT.A = Cm3; dT.aOff0 = 0; dT.aOff1 = 2097152; dT.aOff2 = 4194304;
    dT.sA = 32768; dT.lda = 256;
    dT.B0 = WCTb; dT.bOff0 = 0; dT.bOff1 = 65536; dT.bOff2 = 131072;
    dT.sB0 = 0; dT.ldb = 256;
    dT.C = Hb3; dT.sC = 32768; dT.ldc = 256; dT.Kd = 256;
    mg<2, 2, 0, 1, 64><<<dim3(2, 2, 192), 256, 0, stream>>>(dT, dT, 192);

    // ---- out: out[b,l,d] = WH^T @ Hb^T + residual ----
    OpDesc dOut = {};
    dOut.A = WHTb; dOut.aOff0 = 0; dOut.aOff1 = 262144; dOut.aOff2 = 524288;
    dOut.sA = 0; dOut.lda = 256;
    dOut.B0 = Hb3; dOut.bOff0 = 0; dOut.bOff1 = 2097152; dOut.bOff2 = 4194304;
    dOut.sB0 = 32768; dOut.ldb = 256;
    dOut.C = d_out; dOut.ldc = 128;
    dOut.E0 = aud; dOut.E1 = vis; dOut.E2 = txt; dOut.Kd = 256;
    mg<3, 3, 0, 1, 128><<<dim3(8, 1, 192), 256, 0, stream>>>(dOut, dOut, 192);
}

// Round 14
// 296.096 us; speedup vs baseline: 1.1977x; 1.1977x over previous
//
#include <hip/hip_runtime.h>
#include <math.h>

typedef __attribute__((ext_vector_type(8))) short bf16x8;
typedef __attribute__((ext_vector_type(4))) float f32x4;

static constexpr int B_ = 64, L_ = 1024, D_ = 128, K_ = 256;
static constexpr long BLD_ = (long)B_ * L_ * D_;      // 8,388,608
static constexpr long LD_  = (long)L_ * D_;           // 131,072

__device__ __forceinline__ unsigned short f2b(float f) {
    unsigned int u = __builtin_bit_cast(unsigned int, f);
    u = (u + 0x7fffu + ((u >> 16) & 1u)) >> 16;
    return (unsigned short)u;
}
__device__ __forceinline__ float b2f(unsigned short h) {
    unsigned int u = ((unsigned int)h) << 16;
    return __builtin_bit_cast(float, u);
}

__device__ __forceinline__ void gl16(const unsigned short* g, unsigned short* s) {
    __builtin_amdgcn_global_load_lds(
        (const __attribute__((address_space(1))) unsigned int*)g,
        (__attribute__((address_space(3))) unsigned int*)s, 16, 0, 0);
}

// ---- fused transpose/convert: fp32 [R][C] -> bf16 [C][R] (tr=1) or [R][C] (tr=0) ----
struct TrEnt { const float* src; unsigned short* dst; int R, C, tr, start; };
struct TrTab { TrEnt e[17]; };

__global__ __launch_bounds__(256)
void trk(TrTab tab)
{
    __shared__ unsigned short T[64][72];
    int bid = blockIdx.x;
    int ei = 0;
    #pragma unroll
    for (int i = 1; i < 17; ++i) if (bid >= tab.e[i].start) ei = i;
    TrEnt e = tab.e[ei];
    int tile = bid - e.start;
    int ntR = e.R >> 6, ntC = e.C >> 6;
    int nt = ntR * ntC;
    int bb = tile / nt, tt = tile - bb * nt;
    int ri = tt % ntR, ci = tt / ntR;
    const float* src = e.src + (long)bb * e.R * e.C + (long)(ri * 64) * e.C + ci * 64;
    int t = threadIdx.x;
    if (!e.tr) {
        unsigned short* dstd = e.dst + (long)bb * e.R * e.C + (long)(ri * 64) * e.C + ci * 64;
        int r = t >> 2, cq = t & 3;
        const float* s = src + (long)r * e.C + cq * 16;
        unsigned short tmp[16];
        #pragma unroll
        for (int f = 0; f < 4; ++f) {
            float4 v = *(const float4*)(s + f * 4);
            tmp[f*4+0]=f2b(v.x); tmp[f*4+1]=f2b(v.y); tmp[f*4+2]=f2b(v.z); tmp[f*4+3]=f2b(v.w);
        }
        unsigned short* dp = dstd + (long)r * e.C + cq * 16;
        *(uint4*)&dp[0] = *(uint4*)&tmp[0];
        *(uint4*)&dp[8] = *(uint4*)&tmp[8];
        return;
    }
    unsigned short* dst = e.dst + (long)bb * e.R * e.C + (long)(ci * 64) * e.R + ri * 64;
    {
        int r = t >> 2, cq = t & 3;
        const float* s = src + (long)r * e.C + cq * 16;
        unsigned short tmp[16];
        #pragma unroll
        for (int f = 0; f < 4; ++f) {
            float4 v = *(const float4*)(s + f * 4);
            tmp[f*4+0]=f2b(v.x); tmp[f*4+1]=f2b(v.y); tmp[f*4+2]=f2b(v.z); tmp[f*4+3]=f2b(v.w);
        }
        *(uint4*)&T[r][cq*16]   = *(uint4*)&tmp[0];
        *(uint4*)&T[r][cq*16+8] = *(uint4*)&tmp[8];
    }
    __syncthreads();
    {
        int cr = t >> 2, rq = t & 3;
        unsigned short tmp[16];
        #pragma unroll
        for (int j = 0; j < 16; ++j) tmp[j] = T[rq*16 + j][cr];
        unsigned short* dp = dst + (long)cr * e.R + rq * 16;
        *(uint4*)&dp[0] = *(uint4*)&tmp[0];
        *(uint4*)&dp[8] = *(uint4*)&tmp[8];
    }
}

// ---------------- unified MFMA GEMM ----------------
struct OpDesc {
    const unsigned short* A;
    long aOff0, aOff1, aOff2, sA;
    int lda;
    const unsigned short* B0;
    long bOff0, bOff1, bOff2, sB0;
    const unsigned short* B1;
    long sB1;
    int ldb;
    void* C;
    long sC;
    int ldc;
    const float* E0; const float* E1; const float* E2;
    float* ss;
    int Kd;
};

// LDS chunk swizzle: LDS(row, ch) holds global chunk ch ^ ((row>>1)&3).
// gl16: linear dest; per-lane SOURCE chunk = (l&3)^((l>>3)&3). Read: rc = (kg^((fr>>1)&3))*8.
// EPI: 0 store bf16; 1 tanh(acc/16)->bf16; 2 relu(acc+C_old)->bf16 inplace;
//      3 fp32 out + residual; 4 bias+pool->bf16 + per-block sumsq partial
// Non-AF32: 3-buffer depth-2 prefetch, counted vmcnt BEFORE raw barrier.
template<int EPI, int AF32, int TM, int NBUF>
__device__ __forceinline__ void gbody(const OpDesc& d, int bx, int by, int zrem,
                                      unsigned short (*As)[TM][32],
                                      unsigned short (*Bs)[128][32])
{
    const int tid = threadIdx.x;
    const long m0 = (long)bx * TM;
    const int n0 = by * 128;
    const int br = zrem >> 6, bb = zrem & 63;

    long aO = (br == 0 ? d.aOff0 : br == 1 ? d.aOff1 : d.aOff2) + (long)bb * d.sA;
    const unsigned short* A_ = d.A + aO;
    const float* Af = (const float*)d.A;
    const unsigned short* Bp;
    int nB = n0;
    if (d.B1 && n0 >= 128) { Bp = d.B1 + (long)bb * d.sB1; nB = n0 - 128; }
    else { Bp = d.B0 + (br == 0 ? d.bOff0 : br == 1 ? d.bOff1 : d.bOff2) + (long)bb * d.sB0; }

    const int w = tid >> 6, l = tid & 63;
    const int wm = (TM == 128) ? (w >> 1) : 0;
    const int wn = (TM == 128) ? (w & 1) : w;
    const int NJ = (TM == 128) ? 4 : 2;
    const int WS = (TM == 128) ? 64 : 32;
    const int fr = l & 15, kg = l >> 4;

    f32x4 acc[4][4];
    #pragma unroll
    for (int i = 0; i < 4; ++i)
        #pragma unroll
        for (int j = 0; j < 4; ++j)
            acc[i][j] = (f32x4){0.f, 0.f, 0.f, 0.f};

    const int sc8 = ((l & 3) ^ ((l >> 3) & 3)) * 8;   // swizzled source chunk offset
    const int rc  = (kg ^ ((fr >> 1) & 3)) * 8;        // swizzled read col

    auto stage = [&](int buf, int k0) {
        if (AF32) {
            int row = tid >> 1, half = tid & 1;
            const float* s = Af + (long)(m0 + row) * d.lda + k0 + half * 16;
            unsigned short tmp[16];
            #pragma unroll
            for (int f = 0; f < 4; ++f) {
                float4 v = *(const float4*)(s + f * 4);
                tmp[f*4+0]=f2b(v.x); tmp[f*4+1]=f2b(v.y); tmp[f*4+2]=f2b(v.z); tmp[f*4+3]=f2b(v.w);
            }
            int sw = (row >> 1) & 3;
            *(uint4*)&As[buf][row][((2*half    ) ^ sw) * 8] = *(uint4*)&tmp[0];
            *(uint4*)&As[buf][row][((2*half + 1) ^ sw) * 8] = *(uint4*)&tmp[8];
        } else if (TM == 128) {
            const unsigned short* ga = A_ + (m0 + 32*w + (l >> 2)) * (long)d.lda + k0 + sc8;
            gl16(ga,                    &As[buf][32*w][0]);
            gl16(ga + 16*(long)d.lda,   &As[buf][32*w + 16][0]);
        } else {
            const unsigned short* ga = A_ + (m0 + 16*w + (l >> 2)) * (long)d.lda + k0 + sc8;
            gl16(ga, &As[buf][16*w][0]);
        }
        const unsigned short* gb = Bp + (long)(nB + 32*w + (l >> 2)) * d.ldb + k0 + sc8;
        gl16(gb,                  &Bs[buf][32*w][0]);
        gl16(gb + 16*(long)d.ldb, &Bs[buf][32*w + 16][0]);
    };

    auto compute = [&](int cb) {
        bf16x8 af[4], bf[4];
        #pragma unroll
        for (int i = 0; i < 4; ++i) af[i] = *(const bf16x8*)&As[cb][wm*64 + i*16 + fr][rc];
        #pragma unroll
        for (int j = 0; j < NJ; ++j) bf[j] = *(const bf16x8*)&Bs[cb][wn*WS + j*16 + fr][rc];
        #pragma unroll
        for (int i = 0; i < 4; ++i)
            #pragma unroll
            for (int j = 0; j < NJ; ++j)
                acc[i][j] = __builtin_amdgcn_mfma_f32_16x16x32_bf16(af[i], bf[j], acc[i][j], 0, 0, 0);
    };

    const int nt = d.Kd >> 5;
    if (AF32) {
        stage(0, 0);
        __syncthreads();
        for (int t = 0; t < nt; ++t) {
            if (t + 1 < nt) stage((t + 1) & 1, (t + 1) << 5);
            compute(t & 1);
            __syncthreads();
        }
    } else {
        // 3-buffer depth-2: per iter { vmcnt(NLD|0); s_barrier; stage(t+2); compute(t) }
        stage(0, 0);
        stage(1, 32);
        int cb = 0, sb = 2;
        for (int t = 0; t < nt; ++t) {
            if (t + 1 < nt) {
                if (TM == 128) asm volatile("s_waitcnt vmcnt(4)" ::: "memory");
                else           asm volatile("s_waitcnt vmcnt(3)" ::: "memory");
            } else {
                asm volatile("s_waitcnt vmcnt(0)" ::: "memory");
            }
            __builtin_amdgcn_s_barrier();
            __builtin_amdgcn_sched_barrier(0);
            if (t + 2 < nt) {
                stage(sb, (t + 2) << 5);
                sb = (sb == 2) ? 0 : sb + 1;
            }
            compute(cb);
            cb = (cb == 2) ? 0 : cb + 1;
        }
        __syncthreads();
    }

    if (EPI == 4) {
        unsigned short* C = (unsigned short*)d.C;
        float lss = 0.f;
        #pragma unroll
        for (int i = 0; i < 4; ++i)
            #pragma unroll
            for (int j = 0; j < 4; ++j) {
                int cg = n0 + wn*64 + j*16 + fr;
                float bias = d.E0[cg];
                #pragma unroll
                for (int r = 0; r < 4; ++r) {
                    float v = acc[i][j][r] + bias;
                    lss += v * v;
                }
            }
        #pragma unroll
        for (int o = 32; o; o >>= 1) lss += __shfl_xor(lss, o);
        __shared__ float red4[4];
        if (l == 0) red4[w] = lss;
        float* eb = (float*)As;
        #pragma unroll
        for (int cc = 0; cc < 4; ++cc) {
            __syncthreads();
            #pragma unroll
            for (int j = 0; j < 4; ++j) {
                int cg = n0 + wn*64 + j*16 + fr;
                float bias = d.E0[cg];
                #pragma unroll
                for (int r = 0; r < 4; ++r)
                    eb[(wm*16 + kg*4 + r)*128 + wn*64 + j*16 + fr] = acc[cc][j][r] + bias;
            }
            __syncthreads();
            int lr = tid >> 3, pc = tid & 7;
            long gr = m0 + (lr < 16 ? cc*16 + lr : 48 + cc*16 + lr);
            unsigned short pk[8];
            #pragma unroll
            for (int e = 0; e < 8; ++e) {
                float v0 = eb[lr*128 + pc*16 + 2*e];
                float v1 = eb[lr*128 + pc*16 + 2*e + 1];
                pk[e] = f2b(v0 + v1);
            }
            *(uint4*)&C[gr * (long)d.ldc + (n0 >> 1) + pc*8] = *(uint4*)&pk[0];
        }
        if (tid == 0)
            d.ss[bx * 2 + by] = red4[0] + red4[1] + red4[2] + red4[3];
    } else if (TM == 64) {
        float* eb = (float*)As;
        #pragma unroll
        for (int cc = 0; cc < 4; ++cc) {
            __syncthreads();
            #pragma unroll
            for (int j = 0; j < 2; ++j)
                #pragma unroll
                for (int r = 0; r < 4; ++r)
                    eb[(kg*4 + r)*128 + wn*32 + j*16 + fr] = acc[cc][j][r];
            __syncthreads();
            unsigned short* C = (unsigned short*)d.C + (long)zrem * d.sC;
            int colx = (tid & 15) * 8;
            int lr = tid >> 4;
            long gr = m0 + cc*16 + lr;
            long gi = gr * (long)d.ldc + n0 + colx;
            unsigned short ov[8];
            if (EPI == 2) *(uint4*)ov = *(const uint4*)&C[gi];
            unsigned short pk[8];
            #pragma unroll
            for (int e = 0; e < 8; ++e) {
                float v = eb[lr*128 + colx + e];
                if (EPI == 1) v = tanhf(v * 0.0625f);
                if (EPI == 2) v = fmaxf(v + b2f(ov[e]), 0.f);
                pk[e] = f2b(v);
            }
            *(uint4*)&C[gi] = *(uint4*)&pk[0];
        }
    } else {
        float* eb = (float*)As;
        #pragma unroll
        for (int cc = 0; cc < 4; ++cc) {
            __syncthreads();
            #pragma unroll
            for (int j = 0; j < 4; ++j)
                #pragma unroll
                for (int r = 0; r < 4; ++r)
                    eb[(wm*16 + kg*4 + r)*128 + wn*64 + j*16 + fr] = acc[cc][j][r];
            __syncthreads();
            if (EPI == 3) {
                long off = (br == 2) ? 0L : (long)(br + 1) * BLD_;
                float* Co = (float*)d.C + off + (long)bb * LD_;
                const float* Ep = (br == 0 ? d.E0 : br == 1 ? d.E1 : d.E2) + (long)bb * LD_;
                int colx = (tid & 31) * 4;
                #pragma unroll
                for (int p = 0; p < 4; ++p) {
                    int lr = (tid >> 5) + 8 * p;
                    long gr = m0 + (lr < 16 ? cc*16 + lr : 48 + cc*16 + lr);
                    long gi = gr * (long)d.ldc + n0 + colx;
                    float4 v = *(float4*)&eb[lr*128 + colx];
                    float4 e4 = *(const float4*)&Ep[gi];
                    v.x += e4.x; v.y += e4.y; v.z += e4.z; v.w += e4.w;
                    *(float4*)&Co[gi] = v;
                }
            } else {
                unsigned short* C = (unsigned short*)d.C + (long)zrem * d.sC;
                int colx = (tid & 15) * 8;
                #pragma unroll
                for (int p = 0; p < 2; ++p) {
                    int lr = (tid >> 4) + 16 * p;
                    long gr = m0 + (lr < 16 ? cc*16 + lr : 48 + cc*16 + lr);
                    long gi = gr * (long)d.ldc + n0 + colx;
                    unsigned short ov[8];
                    if (EPI == 2) *(uint4*)ov = *(const uint4*)&C[gi];
                    unsigned short pk[8];
                    #pragma unroll
                    for (int e = 0; e < 8; ++e) {
                        float v = eb[lr*128 + colx + e];
                        if (EPI == 1) v = tanhf(v * 0.0625f);
                        if (EPI == 2) v = fmaxf(v + b2f(ov[e]), 0.f);
                        pk[e] = f2b(v);
                    }
                    *(uint4*)&C[gi] = *(uint4*)&pk[0];
                }
            }
        }
    }
}

// SWZ=1: XCD-aware bijective remap (requires nwg % 8 == 0)
template<int EPI0, int EPI1, int AF32, int SWZ, int TM>
__global__ __launch_bounds__(256)
void mg(OpDesc d0, OpDesc d1, int zsplit)
{
    constexpr int NBUF = AF32 ? 2 : 3;
    __shared__ __align__(16) unsigned short As[NBUF][TM][32];
    __shared__ __align__(16) unsigned short Bs[NBUF][128][32];
    int bx, by, bz;
    if (SWZ) {
        int nwg = gridDim.x * gridDim.y * gridDim.z;
        int c = blockIdx.x + gridDim.x * (blockIdx.y + gridDim.y * blockIdx.z);
        int lid = (c & 7) * (nwg >> 3) + (c >> 3);
        bx = lid % gridDim.x; lid /= gridDim.x;
        by = lid % gridDim.y; bz = lid / gridDim.y;
    } else {
        bx = blockIdx.x; by = blockIdx.y; bz = blockIdx.z;
    }
    if (bz < zsplit) gbody<EPI0, AF32, TM, NBUF>(d0, bx, by, bz, As, Bs);
    else             gbody<EPI1, AF32, TM, NBUF>(d1, bx, by, bz - zsplit, As, Bs);
}

// z = al*q1 + be*q2 (bf16 in place on q1) + per-(b,lc) column sumsq partials (no atomics)
__global__ __launch_bounds__(256)
void k2z(unsigned short* __restrict__ q1, const unsigned short* __restrict__ q2,
         const float* __restrict__ partial, float* __restrict__ colssP)
{
    int t = threadIdx.x;
    float a = partial[t] + partial[t + 256] + partial[t + 512] + partial[t + 768];
    float bsum = partial[1024 + t] + partial[1280 + t] + partial[1536 + t] + partial[1792 + t];
    #pragma unroll
    for (int o = 32; o; o >>= 1) { a += __shfl_xor(a, o); bsum += __shfl_xor(bsum, o); }
    __shared__ float ra[4], rb[4];
    int wv = t >> 6;
    if ((t & 63) == 0) { ra[wv] = a; rb[wv] = bsum; }
    __syncthreads();
    float n1 = sqrtf(ra[0] + ra[1] + ra[2] + ra[3]);
    float n2 = sqrtf(rb[0] + rb[1] + rb[2] + rb[3]);
    float al = n1 / (n1 + n2), be = n2 / (n1 + n2);

    int b = blockIdx.x, lc = blockIdx.y;
    int d = t & 127, ls = t >> 7;
    long base = ((long)b * L_ + (long)lc * 64) * D_;
    float acc = 0.f;
    for (int ll = ls; ll < 64; ll += 2) {
        long idx = base + (long)ll * D_ + d;
        float zv = al * b2f(q1[idx]) + be * b2f(q2[idx]);
        q1[idx] = f2b(zv);
        acc += zv * zv;
    }
    __shared__ float red[256];
    red[t] = acc;
    __syncthreads();
    if (t < 128)
        colssP[((long)b * 16 + lc) * 128 + d] = red[t] + red[t + 128];
}

// GT[b][d][l] = z[b][l][d] / max(sqrt(sum_lc colssP[b][lc][d]),1e-12)
__global__ __launch_bounds__(256)
void k3nT(const unsigned short* __restrict__ z, const float* __restrict__ colssP,
          unsigned short* __restrict__ GT)
{
    __shared__ unsigned short T[128][136];
    int b = blockIdx.x, lt = blockIdx.y;
    int t = threadIdx.x;
    {
        int r = t >> 1, half = t & 1;
        const unsigned short* src = z + ((long)b * L_ + lt * 128 + r) * D_ + half * 64;
        #pragma unroll
        for (int q = 0; q < 8; ++q)
            *(uint4*)&T[r][half*64 + q*8] = *(const uint4*)(src + q*8);
    }
    __syncthreads();
    {
        int d = t >> 1, lh = t & 1;
        float s = 0.f;
        #pragma unroll
        for (int lc = 0; lc < 16; ++lc)
            s += colssP[((long)b * 16 + lc) * 128 + d];
        float inv = 1.f / fmaxf(sqrtf(s), 1e-12f);
        unsigned short tmp[64];
        #pragma unroll
        for (int j = 0; j < 64; ++j) tmp[j] = f2b(b2f(T[lh*64 + j][d]) * inv);
        unsigned short* dp = GT + ((long)b * D_ + d) * L_ + lt * 128 + lh * 64;
        #pragma unroll
        for (int q = 0; q < 8; ++q) *(uint4*)&dp[q*8] = *(uint4*)&tmp[q*8];
    }
}

extern "C" void kernel_launch(void* const* d_in, const int* in_sizes, int n_in,
                              void* d_out, int out_size, void* d_ws, size_t ws_size,
                              hipStream_t stream)
{
    const float* txt = (const float*)d_in[0];
    const float* aud = (const float*)d_in[1];
    const float* vis = (const float*)d_in[2];
    const float* Wi  = (const float*)d_in[3];
    const float* bi  = (const float*)d_in[4];
    const float* Wq  = (const float*)d_in[5];
    const float* bq  = (const float*)d_in[6];
    const float* Waff[3] = { (const float*)d_in[7], (const float*)d_in[8], (const float*)d_in[9] };
    const float* Wlin[3] = { (const float*)d_in[10], (const float*)d_in[11], (const float*)d_in[12] };
    const float* Wc[3]   = { (const float*)d_in[13], (const float*)d_in[14], (const float*)d_in[15] };
    const float* Wh[3]   = { (const float*)d_in[16], (const float*)d_in[17], (const float*)d_in[18] };

    // ---- workspace (bf16 elems) ----
    unsigned short* w16 = (unsigned short*)d_ws;
    unsigned short* featT = w16;                      // 3*BLD  [aud,vis,txt] x [b][d][l]
    unsigned short* q1b   = featT + 3 * BLD_;         // 8,388,608
    unsigned short* q2b   = q1b + BLD_;               // 8,388,608
    unsigned short* WAb   = q2b + BLD_;               // 3,145,728
    unsigned short* WLTb  = WAb + 3145728;            // 786,432
    unsigned short* WCTb  = WLTb + 786432;            // 196,608
    unsigned short* WHTb  = WCTb + 196608;            // 786,432
    unsigned short* WiTb  = WHTb + 786432;            // 32,768
    unsigned short* WqTb  = WiTb + 32768;             // 32,768
    float* partial = (float*)(WqTb + 32768);          // 2048 block partials
    float* colssP  = partial + 2048;                  // 131,072 partials
    // overlays (q1/q2 dead after k3nT)
    unsigned short* Cm3 = q1b;                        // 6,291,456
    unsigned short* Hb3 = q1b + 6291456;              // 6,291,456
    // d_out scratch (fully overwritten by final GEMM)
    unsigned short* S2all = (unsigned short*)d_out;   // 25,165,824
    unsigned short* GT    = S2all + 3 * BLD_;         // 8,388,608

    // ---- transposes/conversions (merged) ----
    TrTab tab;
    auto setE = [&](int i, const float* s, unsigned short* dst, int R, int C, int tr, int start) {
        tab.e[i].src = s; tab.e[i].dst = dst; tab.e[i].R = R; tab.e[i].C = C;
        tab.e[i].tr = tr; tab.e[i].start = start;
    };
    int st = 0;
    setE(0, aud, featT + 0,        1024, 128, 1, st); st += 2048;
    setE(1, vis, featT + BLD_,     1024, 128, 1, st); st += 2048;
    setE(2, txt, featT + 2 * BLD_, 1024, 128, 1, st); st += 2048;
    setE(3, Wi, WiTb, 128, 256, 1, st); st += 8;
    setE(4, Wq, WqTb, 128, 256, 1, st); st += 8;
    for (int i = 0; i < 3; ++i) { setE(5 + i, Wlin[i], WLTb + (long)i * 262144, 1024, 256, 1, st); st += 64; }
    for (int i = 0; i < 3; ++i) { setE(8 + i, Wc[i],   WCTb + (long)i * 65536,  256, 256, 1, st); st += 16; }
    for (int i = 0; i < 3; ++i) { setE(11 + i, Wh[i],  WHTb + (long)i * 262144, 256, 1024, 1, st); st += 64; }
    for (int i = 0; i < 3; ++i) { setE(14 + i, Waff[i], WAb + (long)i * 1048576, 1024, 1024, 0, st); st += 256; }
    trk<<<st, 256, 0, stream>>>(tab);

    // ---- BiAMLP (txt|aud merged, fp32-A LDS path) ----
    OpDesc dTxt = {}, dAud = {};
    dTxt.A = (const unsigned short*)txt; dTxt.lda = 128;
    dTxt.B0 = WiTb; dTxt.ldb = 128;
    dTxt.C = q1b; dTxt.ldc = 128;
    dTxt.E0 = bi; dTxt.ss = partial; dTxt.Kd = 128;
    dAud = dTxt;
    dAud.A = (const unsigned short*)aud; dAud.B0 = WqTb; dAud.C = q2b;
    dAud.E0 = bq; dAud.ss = partial + 1024;
    mg<4, 4, 1, 0, 128><<<dim3(512, 2, 2), 256, 0, stream>>>(dTxt, dAud, 1);

    k2z<<<dim3(64, 16), 256, 0, stream>>>(q1b, q2b, partial, colssP);
    k3nT<<<dim3(64, 8), 256, 0, stream>>>(q1b, colssP, GT);

    // ---- S2[br][b][d][l] = featT[br][b] @ WA[br] ----
    OpDesc dS2 = {};
    dS2.A = featT; dS2.aOff0 = 0; dS2.aOff1 = BLD_; dS2.aOff2 = 2 * BLD_;
    dS2.sA = LD_; dS2.lda = 1024;
    dS2.B0 = WAb; dS2.bOff0 = 0; dS2.bOff1 = 1048576; dS2.bOff2 = 2097152;
    dS2.sB0 = 0; dS2.ldb = 1024;
    dS2.C = S2all; dS2.sC = LD_; dS2.ldc = 1024; dS2.Kd = 1024;
    mg<0, 0, 0, 1, 128><<<dim3(1, 8, 192), 256, 0, stream>>>(dS2, dS2, 192);

    // ---- att (tanh) + U merged: 64-row tiles ----
    OpDesc dAtt = {};
    dAtt.A = S2all; dAtt.aOff0 = 0; dAtt.aOff1 = 64 * LD_; dAtt.aOff2 = 128 * LD_;
    dAtt.sA = LD_; dAtt.lda = 1024;
    dAtt.B0 = featT; dAtt.bOff0 = 0; dAtt.bOff1 = 0; dAtt.bOff2 = 2 * BLD_;  // audT,audT,txtT
    dAtt.sB0 = LD_;
    dAtt.B1 = GT; dAtt.sB1 = LD_; dAtt.ldb = 1024;
    dAtt.C = Cm3; dAtt.sC = 32768; dAtt.ldc = 256; dAtt.Kd = 1024;
    OpDesc dU = {};
    dU.A = featT; dU.aOff0 = 0; dU.aOff1 = BLD_; dU.aOff2 = 2 * BLD_;
    dU.sA = LD_; dU.lda = 1024;
    dU.B0 = WLTb; dU.bOff0 = 0; dU.bOff1 = 262144; dU.bOff2 = 524288;
    dU.sB0 = 0; dU.ldb = 1024;
    dU.C = Hb3; dU.sC = 32768; dU.ldc = 256; dU.Kd = 1024;
    mg<1, 0, 0, 1, 64><<<dim3(2, 2, 384), 256, 0, stream>>>(dAtt, dU, 192);

    // ---- T: Hb = relu(Cm @ WC + Hb): 64-row tiles ----
    OpDesc dT = {};
    dT.A = Cm3; dT.aOff0 = 0; dT.aOff1 = 2097152; dT.aOff2 = 4194304;
    dT.sA = 32768; dT.lda = 256;
    dT.B0 = WCTb; dT.bOff0 = 0; dT.bOff1 = 65536; dT.bOff2 = 131072;
    dT.sB0 = 0; dT.ldb = 256;
    dT.C = Hb3; dT.sC = 32768; dT.ldc = 256; dT.Kd = 256;
    mg<2, 2, 0, 1, 64><<<dim3(2, 2, 192), 256, 0, stream>>>(dT, dT, 192);

    // ---- out: out[b,l,d] = WH^T @ Hb^T + residual ----
    OpDesc dOut = {};
    dOut.A = WHTb; dOut.aOff0 = 0; dOut.aOff1 = 262144; dOut.aOff2 = 524288;
    dOut.sA = 0; dOut.lda = 256;
    dOut.B0 = Hb3; dOut.bOff0 = 0; dOut.bOff1 = 2097152; dOut.bOff2 = 4194304;
    dOut.sB0 = 32768; dOut.ldb = 256;
    dOut.C = d_out; dOut.ldc = 128;
    dOut.E0 = aud; dOut.E1 = vis; dOut.E2 = txt; dOut.Kd = 256;
    mg<3, 3, 0, 1, 128><<<dim3(8, 1, 192), 256, 0, stream>>>(dOut, dOut, 192);
}

// Round 15
// 290.927 us; speedup vs baseline: 1.2190x; 1.0178x over previous
//
#include <hip/hip_runtime.h>
#include <math.h>

typedef __attribute__((ext_vector_type(8))) short bf16x8;
typedef __attribute__((ext_vector_type(4))) float f32x4;

static constexpr int B_ = 64, L_ = 1024, D_ = 128, K_ = 256;
static constexpr long BLD_ = (long)B_ * L_ * D_;      // 8,388,608
static constexpr long LD_  = (long)L_ * D_;           // 131,072

__device__ __forceinline__ unsigned short f2b(float f) {
    unsigned int u = __builtin_bit_cast(unsigned int, f);
    u = (u + 0x7fffu + ((u >> 16) & 1u)) >> 16;
    return (unsigned short)u;
}
__device__ __forceinline__ float b2f(unsigned short h) {
    unsigned int u = ((unsigned int)h) << 16;
    return __builtin_bit_cast(float, u);
}

__device__ __forceinline__ void gl16(const unsigned short* g, unsigned short* s) {
    __builtin_amdgcn_global_load_lds(
        (const __attribute__((address_space(1))) unsigned int*)g,
        (__attribute__((address_space(3))) unsigned int*)s, 16, 0, 0);
}

// ---- fused transpose/convert: fp32 [R][C] -> bf16 [C][R] (tr=1) or [R][C] (tr=0) ----
struct TrEnt { const float* src; unsigned short* dst; int R, C, tr, start; };
struct TrTab { TrEnt e[17]; };

__global__ __launch_bounds__(256)
void trk(TrTab tab)
{
    __shared__ unsigned short T[64][72];
    int bid = blockIdx.x;
    int ei = 0;
    #pragma unroll
    for (int i = 1; i < 17; ++i) if (bid >= tab.e[i].start) ei = i;
    TrEnt e = tab.e[ei];
    int tile = bid - e.start;
    int ntR = e.R >> 6, ntC = e.C >> 6;
    int nt = ntR * ntC;
    int bb = tile / nt, tt = tile - bb * nt;
    int ri = tt % ntR, ci = tt / ntR;
    const float* src = e.src + (long)bb * e.R * e.C + (long)(ri * 64) * e.C + ci * 64;
    int t = threadIdx.x;
    if (!e.tr) {
        unsigned short* dstd = e.dst + (long)bb * e.R * e.C + (long)(ri * 64) * e.C + ci * 64;
        int r = t >> 2, cq = t & 3;
        const float* s = src + (long)r * e.C + cq * 16;
        unsigned short tmp[16];
        #pragma unroll
        for (int f = 0; f < 4; ++f) {
            float4 v = *(const float4*)(s + f * 4);
            tmp[f*4+0]=f2b(v.x); tmp[f*4+1]=f2b(v.y); tmp[f*4+2]=f2b(v.z); tmp[f*4+3]=f2b(v.w);
        }
        unsigned short* dp = dstd + (long)r * e.C + cq * 16;
        *(uint4*)&dp[0] = *(uint4*)&tmp[0];
        *(uint4*)&dp[8] = *(uint4*)&tmp[8];
        return;
    }
    unsigned short* dst = e.dst + (long)bb * e.R * e.C + (long)(ci * 64) * e.R + ri * 64;
    {
        int r = t >> 2, cq = t & 3;
        const float* s = src + (long)r * e.C + cq * 16;
        unsigned short tmp[16];
        #pragma unroll
        for (int f = 0; f < 4; ++f) {
            float4 v = *(const float4*)(s + f * 4);
            tmp[f*4+0]=f2b(v.x); tmp[f*4+1]=f2b(v.y); tmp[f*4+2]=f2b(v.z); tmp[f*4+3]=f2b(v.w);
        }
        *(uint4*)&T[r][cq*16]   = *(uint4*)&tmp[0];
        *(uint4*)&T[r][cq*16+8] = *(uint4*)&tmp[8];
    }
    __syncthreads();
    {
        int cr = t >> 2, rq = t & 3;
        unsigned short tmp[16];
        #pragma unroll
        for (int j = 0; j < 16; ++j) tmp[j] = T[rq*16 + j][cr];
        unsigned short* dp = dst + (long)cr * e.R + rq * 16;
        *(uint4*)&dp[0] = *(uint4*)&tmp[0];
        *(uint4*)&dp[8] = *(uint4*)&tmp[8];
    }
}

// ---------------- unified MFMA GEMM ----------------
struct OpDesc {
    const unsigned short* A;
    long aOff0, aOff1, aOff2, sA;
    int lda;
    const unsigned short* B0;
    long bOff0, bOff1, bOff2, sB0;
    const unsigned short* B1;
    long sB1;
    int ldb;
    void* C;
    long sC;
    int ldc;
    const float* E0; const float* E1; const float* E2;
    float* ss;
    int Kd;
};

// LDS chunk swizzle: LDS(row, ch) holds global chunk ch ^ ((row>>1)&3).
// gl16: linear dest; per-lane SOURCE chunk = (l&3)^((l>>3)&3). Read: rc = (kg^((fr>>1)&3))*8.
// EPI: 0 store bf16; 1 tanh(acc/16)->bf16; 2 relu(acc+C_old)->bf16 inplace;
//      3 fp32 out + residual; 4 bias+pool->bf16 + per-block sumsq partial
template<int EPI, int AF32, int TM>
__device__ __forceinline__ void gbody(const OpDesc& d, int bx, int by, int zrem,
                                      unsigned short (*As)[TM][32],
                                      unsigned short (*Bs)[128][32])
{
    const int tid = threadIdx.x;
    const long m0 = (long)bx * TM;
    const int n0 = by * 128;
    const int br = zrem >> 6, bb = zrem & 63;

    long aO = (br == 0 ? d.aOff0 : br == 1 ? d.aOff1 : d.aOff2) + (long)bb * d.sA;
    const unsigned short* A_ = d.A + aO;
    const float* Af = (const float*)d.A;
    const unsigned short* Bp;
    int nB = n0;
    if (d.B1 && n0 >= 128) { Bp = d.B1 + (long)bb * d.sB1; nB = n0 - 128; }
    else { Bp = d.B0 + (br == 0 ? d.bOff0 : br == 1 ? d.bOff1 : d.bOff2) + (long)bb * d.sB0; }

    const int w = tid >> 6, l = tid & 63;
    const int wm = (TM == 128) ? (w >> 1) : 0;
    const int wn = (TM == 128) ? (w & 1) : w;
    const int NJ = (TM == 128) ? 4 : 2;
    const int WS = (TM == 128) ? 64 : 32;
    const int fr = l & 15, kg = l >> 4;

    f32x4 acc[4][4];
    #pragma unroll
    for (int i = 0; i < 4; ++i)
        #pragma unroll
        for (int j = 0; j < 4; ++j)
            acc[i][j] = (f32x4){0.f, 0.f, 0.f, 0.f};

    const int sc8 = ((l & 3) ^ ((l >> 3) & 3)) * 8;   // swizzled source chunk offset
    const int rc  = (kg ^ ((fr >> 1) & 3)) * 8;        // swizzled read col

    auto stage = [&](int buf, int k0) {
        if (AF32) {
            int row = tid >> 1, half = tid & 1;
            const float* s = Af + (long)(m0 + row) * d.lda + k0 + half * 16;
            unsigned short tmp[16];
            #pragma unroll
            for (int f = 0; f < 4; ++f) {
                float4 v = *(const float4*)(s + f * 4);
                tmp[f*4+0]=f2b(v.x); tmp[f*4+1]=f2b(v.y); tmp[f*4+2]=f2b(v.z); tmp[f*4+3]=f2b(v.w);
            }
            int sw = (row >> 1) & 3;
            *(uint4*)&As[buf][row][((2*half    ) ^ sw) * 8] = *(uint4*)&tmp[0];
            *(uint4*)&As[buf][row][((2*half + 1) ^ sw) * 8] = *(uint4*)&tmp[8];
        } else if (TM == 128) {
            const unsigned short* ga = A_ + (m0 + 32*w + (l >> 2)) * (long)d.lda + k0 + sc8;
            gl16(ga,                    &As[buf][32*w][0]);
            gl16(ga + 16*(long)d.lda,   &As[buf][32*w + 16][0]);
        } else {
            const unsigned short* ga = A_ + (m0 + 16*w + (l >> 2)) * (long)d.lda + k0 + sc8;
            gl16(ga, &As[buf][16*w][0]);
        }
        const unsigned short* gb = Bp + (long)(nB + 32*w + (l >> 2)) * d.ldb + k0 + sc8;
        gl16(gb,                  &Bs[buf][32*w][0]);
        gl16(gb + 16*(long)d.ldb, &Bs[buf][32*w + 16][0]);
    };

    auto compute = [&](int cb) {
        bf16x8 af[4], bf[4];
        #pragma unroll
        for (int i = 0; i < 4; ++i) af[i] = *(const bf16x8*)&As[cb][wm*64 + i*16 + fr][rc];
        #pragma unroll
        for (int j = 0; j < NJ; ++j) bf[j] = *(const bf16x8*)&Bs[cb][wn*WS + j*16 + fr][rc];
        #pragma unroll
        for (int i = 0; i < 4; ++i)
            #pragma unroll
            for (int j = 0; j < NJ; ++j)
                acc[i][j] = __builtin_amdgcn_mfma_f32_16x16x32_bf16(af[i], bf[j], acc[i][j], 0, 0, 0);
    };

    const int nt = d.Kd >> 5;
    stage(0, 0);
    __syncthreads();
    for (int t = 0; t < nt; ++t) {
        if (t + 1 < nt) stage((t + 1) & 1, (t + 1) << 5);
        compute(t & 1);
        __syncthreads();
    }

    if (EPI == 4) {
        unsigned short* C = (unsigned short*)d.C;
        float lss = 0.f;
        #pragma unroll
        for (int i = 0; i < 4; ++i)
            #pragma unroll
            for (int j = 0; j < 4; ++j) {
                int cg = n0 + wn*64 + j*16 + fr;
                float bias = d.E0[cg];
                #pragma unroll
                for (int r = 0; r < 4; ++r) {
                    float v = acc[i][j][r] + bias;
                    lss += v * v;
                }
            }
        #pragma unroll
        for (int o = 32; o; o >>= 1) lss += __shfl_xor(lss, o);
        __shared__ float red4[4];
        if (l == 0) red4[w] = lss;
        float* eb = (float*)As;
        #pragma unroll
        for (int cc = 0; cc < 4; ++cc) {
            __syncthreads();
            #pragma unroll
            for (int j = 0; j < 4; ++j) {
                int cg = n0 + wn*64 + j*16 + fr;
                float bias = d.E0[cg];
                #pragma unroll
                for (int r = 0; r < 4; ++r)
                    eb[(wm*16 + kg*4 + r)*128 + wn*64 + j*16 + fr] = acc[cc][j][r] + bias;
            }
            __syncthreads();
            int lr = tid >> 3, pc = tid & 7;
            long gr = m0 + (lr < 16 ? cc*16 + lr : 48 + cc*16 + lr);
            unsigned short pk[8];
            #pragma unroll
            for (int e = 0; e < 8; ++e) {
                float v0 = eb[lr*128 + pc*16 + 2*e];
                float v1 = eb[lr*128 + pc*16 + 2*e + 1];
                pk[e] = f2b(v0 + v1);
            }
            *(uint4*)&C[gr * (long)d.ldc + (n0 >> 1) + pc*8] = *(uint4*)&pk[0];
        }
        if (tid == 0)
            d.ss[bx * 2 + by] = red4[0] + red4[1] + red4[2] + red4[3];
    } else if (TM == 64) {
        float* eb = (float*)As;
        #pragma unroll
        for (int cc = 0; cc < 4; ++cc) {
            __syncthreads();
            #pragma unroll
            for (int j = 0; j < 2; ++j)
                #pragma unroll
                for (int r = 0; r < 4; ++r)
                    eb[(kg*4 + r)*128 + wn*32 + j*16 + fr] = acc[cc][j][r];
            __syncthreads();
            unsigned short* C = (unsigned short*)d.C + (long)zrem * d.sC;
            int colx = (tid & 15) * 8;
            int lr = tid >> 4;
            long gr = m0 + cc*16 + lr;
            long gi = gr * (long)d.ldc + n0 + colx;
            unsigned short ov[8];
            if (EPI == 2) *(uint4*)ov = *(const uint4*)&C[gi];
            unsigned short pk[8];
            #pragma unroll
            for (int e = 0; e < 8; ++e) {
                float v = eb[lr*128 + colx + e];
                if (EPI == 1) v = tanhf(v * 0.0625f);
                if (EPI == 2) v = fmaxf(v + b2f(ov[e]), 0.f);
                pk[e] = f2b(v);
            }
            *(uint4*)&C[gi] = *(uint4*)&pk[0];
        }
    } else {
        float* eb = (float*)As;
        #pragma unroll
        for (int cc = 0; cc < 4; ++cc) {
            __syncthreads();
            #pragma unroll
            for (int j = 0; j < 4; ++j)
                #pragma unroll
                for (int r = 0; r < 4; ++r)
                    eb[(wm*16 + kg*4 + r)*128 + wn*64 + j*16 + fr] = acc[cc][j][r];
            __syncthreads();
            if (EPI == 3) {
                long off = (br == 2) ? 0L : (long)(br + 1) * BLD_;
                float* Co = (float*)d.C + off + (long)bb * LD_;
                const float* Ep = (br == 0 ? d.E0 : br == 1 ? d.E1 : d.E2) + (long)bb * LD_;
                int colx = (tid & 31) * 4;
                #pragma unroll
                for (int p = 0; p < 4; ++p) {
                    int lr = (tid >> 5) + 8 * p;
                    long gr = m0 + (lr < 16 ? cc*16 + lr : 48 + cc*16 + lr);
                    long gi = gr * (long)d.ldc + n0 + colx;
                    float4 v = *(float4*)&eb[lr*128 + colx];
                    float4 e4 = *(const float4*)&Ep[gi];
                    v.x += e4.x; v.y += e4.y; v.z += e4.z; v.w += e4.w;
                    *(float4*)&Co[gi] = v;
                }
            } else {
                unsigned short* C = (unsigned short*)d.C + (long)zrem * d.sC;
                int colx = (tid & 15) * 8;
                #pragma unroll
                for (int p = 0; p < 2; ++p) {
                    int lr = (tid >> 4) + 16 * p;
                    long gr = m0 + (lr < 16 ? cc*16 + lr : 48 + cc*16 + lr);
                    long gi = gr * (long)d.ldc + n0 + colx;
                    unsigned short ov[8];
                    if (EPI == 2) *(uint4*)ov = *(const uint4*)&C[gi];
                    unsigned short pk[8];
                    #pragma unroll
                    for (int e = 0; e < 8; ++e) {
                        float v = eb[lr*128 + colx + e];
                        if (EPI == 1) v = tanhf(v * 0.0625f);
                        if (EPI == 2) v = fmaxf(v + b2f(ov[e]), 0.f);
                        pk[e] = f2b(v);
                    }
                    *(uint4*)&C[gi] = *(uint4*)&pk[0];
                }
            }
        }
    }
}

// SWZ=1: XCD-aware bijective remap (requires nwg % 8 == 0); split on z
template<int EPI0, int EPI1, int AF32, int SWZ, int TM>
__global__ __launch_bounds__(256)
void mg(OpDesc d0, OpDesc d1, int zsplit)
{
    __shared__ __align__(16) unsigned short As[2][TM][32];
    __shared__ __align__(16) unsigned short Bs[2][128][32];
    int bx, by, bz;
    if (SWZ) {
        int nwg = gridDim.x * gridDim.y * gridDim.z;
        int c = blockIdx.x + gridDim.x * (blockIdx.y + gridDim.y * blockIdx.z);
        int lid = (c & 7) * (nwg >> 3) + (c >> 3);
        bx = lid % gridDim.x; lid /= gridDim.x;
        by = lid % gridDim.y; bz = lid / gridDim.y;
    } else {
        bx = blockIdx.x; by = blockIdx.y; bz = blockIdx.z;
    }
    if (bz < zsplit) gbody<EPI0, AF32, TM>(d0, bx, by, bz, As, Bs);
    else             gbody<EPI1, AF32, TM>(d1, bx, by, bz - zsplit, As, Bs);
}

// split on y: by<ysplit -> d0, else d1 with by-=ysplit (shared-A merge: S2 || U)
template<int EPI0, int EPI1, int SWZ, int TM>
__global__ __launch_bounds__(256)
void mgy(OpDesc d0, OpDesc d1, int ysplit)
{
    __shared__ __align__(16) unsigned short As[2][TM][32];
    __shared__ __align__(16) unsigned short Bs[2][128][32];
    int bx, by, bz;
    if (SWZ) {
        int nwg = gridDim.x * gridDim.y * gridDim.z;
        int c = blockIdx.x + gridDim.x * (blockIdx.y + gridDim.y * blockIdx.z);
        int lid = (c & 7) * (nwg >> 3) + (c >> 3);
        bx = lid % gridDim.x; lid /= gridDim.x;
        by = lid % gridDim.y; bz = lid / gridDim.y;
    } else {
        bx = blockIdx.x; by = blockIdx.y; bz = blockIdx.z;
    }
    if (by < ysplit) gbody<EPI0, 0, TM>(d0, bx, by, bz, As, Bs);
    else             gbody<EPI1, 0, TM>(d1, bx, by - ysplit, bz, As, Bs);
}

// z = al*q1 + be*q2 (bf16 in place on q1) + per-(b,lc) column sumsq partials (no atomics)
__global__ __launch_bounds__(256)
void k2z(unsigned short* __restrict__ q1, const unsigned short* __restrict__ q2,
         const float* __restrict__ partial, float* __restrict__ colssP)
{
    int t = threadIdx.x;
    float a = partial[t] + partial[t + 256] + partial[t + 512] + partial[t + 768];
    float bsum = partial[1024 + t] + partial[1280 + t] + partial[1536 + t] + partial[1792 + t];
    #pragma unroll
    for (int o = 32; o; o >>= 1) { a += __shfl_xor(a, o); bsum += __shfl_xor(bsum, o); }
    __shared__ float ra[4], rb[4];
    int wv = t >> 6;
    if ((t & 63) == 0) { ra[wv] = a; rb[wv] = bsum; }
    __syncthreads();
    float n1 = sqrtf(ra[0] + ra[1] + ra[2] + ra[3]);
    float n2 = sqrtf(rb[0] + rb[1] + rb[2] + rb[3]);
    float al = n1 / (n1 + n2), be = n2 / (n1 + n2);

    int b = blockIdx.x, lc = blockIdx.y;
    int d = t & 127, ls = t >> 7;
    long base = ((long)b * L_ + (long)lc * 64) * D_;
    float acc = 0.f;
    for (int ll = ls; ll < 64; ll += 2) {
        long idx = base + (long)ll * D_ + d;
        float zv = al * b2f(q1[idx]) + be * b2f(q2[idx]);
        q1[idx] = f2b(zv);
        acc += zv * zv;
    }
    __shared__ float red[256];
    red[t] = acc;
    __syncthreads();
    if (t < 128)
        colssP[((long)b * 16 + lc) * 128 + d] = red[t] + red[t + 128];
}

// GT[b][d][l] = z[b][l][d] / max(sqrt(sum_lc colssP[b][lc][d]),1e-12)
__global__ __launch_bounds__(256)
void k3nT(const unsigned short* __restrict__ z, const float* __restrict__ colssP,
          unsigned short* __restrict__ GT)
{
    __shared__ unsigned short T[128][136];
    int b = blockIdx.x, lt = blockIdx.y;
    int t = threadIdx.x;
    {
        int r = t >> 1, half = t & 1;
        const unsigned short* src = z + ((long)b * L_ + lt * 128 + r) * D_ + half * 64;
        #pragma unroll
        for (int q = 0; q < 8; ++q)
            *(uint4*)&T[r][half*64 + q*8] = *(const uint4*)(src + q*8);
    }
    __syncthreads();
    {
        int d = t >> 1, lh = t & 1;
        float s = 0.f;
        #pragma unroll
        for (int lc = 0; lc < 16; ++lc)
            s += colssP[((long)b * 16 + lc) * 128 + d];
        float inv = 1.f / fmaxf(sqrtf(s), 1e-12f);
        unsigned short tmp[64];
        #pragma unroll
        for (int j = 0; j < 64; ++j) tmp[j] = f2b(b2f(T[lh*64 + j][d]) * inv);
        unsigned short* dp = GT + ((long)b * D_ + d) * L_ + lt * 128 + lh * 64;
        #pragma unroll
        for (int q = 0; q < 8; ++q) *(uint4*)&dp[q*8] = *(uint4*)&tmp[q*8];
    }
}

extern "C" void kernel_launch(void* const* d_in, const int* in_sizes, int n_in,
                              void* d_out, int out_size, void* d_ws, size_t ws_size,
                              hipStream_t stream)
{
    const float* txt = (const float*)d_in[0];
    const float* aud = (const float*)d_in[1];
    const float* vis = (const float*)d_in[2];
    const float* Wi  = (const float*)d_in[3];
    const float* bi  = (const float*)d_in[4];
    const float* Wq  = (const float*)d_in[5];
    const float* bq  = (const float*)d_in[6];
    const float* Waff[3] = { (const float*)d_in[7], (const float*)d_in[8], (const float*)d_in[9] };
    const float* Wlin[3] = { (const float*)d_in[10], (const float*)d_in[11], (const float*)d_in[12] };
    const float* Wc[3]   = { (const float*)d_in[13], (const float*)d_in[14], (const float*)d_in[15] };
    const float* Wh[3]   = { (const float*)d_in[16], (const float*)d_in[17], (const float*)d_in[18] };

    // ---- workspace (bf16 elems) ----
    unsigned short* w16 = (unsigned short*)d_ws;
    unsigned short* featT = w16;                      // 3*BLD  [aud,vis,txt] x [b][d][l]
    unsigned short* q1b   = featT + 3 * BLD_;         // 8,388,608
    unsigned short* q2b   = q1b + BLD_;               // 8,388,608
    unsigned short* WAb   = q2b + BLD_;               // 3,145,728
    unsigned short* WLTb  = WAb + 3145728;            // 786,432
    unsigned short* WCTb  = WLTb + 786432;            // 196,608
    unsigned short* WHTb  = WCTb + 196608;            // 786,432
    unsigned short* WiTb  = WHTb + 786432;            // 32,768
    unsigned short* WqTb  = WiTb + 32768;             // 32,768
    float* partial = (float*)(WqTb + 32768);          // 2048 block partials
    float* colssP  = partial + 2048;                  // 131,072 partials
    // overlays (q1/q2 dead after k3nT)
    unsigned short* Cm3 = q1b;                        // 6,291,456
    unsigned short* Hb3 = q1b + 6291456;              // 6,291,456
    // d_out scratch (fully overwritten by final GEMM)
    unsigned short* S2all = (unsigned short*)d_out;   // 25,165,824
    unsigned short* GT    = S2all + 3 * BLD_;         // 8,388,608

    // ---- transposes/conversions (merged) ----
    TrTab tab;
    auto setE = [&](int i, const float* s, unsigned short* dst, int R, int C, int tr, int start) {
        tab.e[i].src = s; tab.e[i].dst = dst; tab.e[i].R = R; tab.e[i].C = C;
        tab.e[i].tr = tr; tab.e[i].start = start;
    };
    int st = 0;
    setE(0, aud, featT + 0,        1024, 128, 1, st); st += 2048;
    setE(1, vis, featT + BLD_,     1024, 128, 1, st); st += 2048;
    setE(2, txt, featT + 2 * BLD_, 1024, 128, 1, st); st += 2048;
    setE(3, Wi, WiTb, 128, 256, 1, st); st += 8;
    setE(4, Wq, WqTb, 128, 256, 1, st); st += 8;
    for (int i = 0; i < 3; ++i) { setE(5 + i, Wlin[i], WLTb + (long)i * 262144, 1024, 256, 1, st); st += 64; }
    for (int i = 0; i < 3; ++i) { setE(8 + i, Wc[i],   WCTb + (long)i * 65536,  256, 256, 1, st); st += 16; }
    for (int i = 0; i < 3; ++i) { setE(11 + i, Wh[i],  WHTb + (long)i * 262144, 256, 1024, 1, st); st += 64; }
    for (int i = 0; i < 3; ++i) { setE(14 + i, Waff[i], WAb + (long)i * 1048576, 1024, 1024, 0, st); st += 256; }
    trk<<<st, 256, 0, stream>>>(tab);

    // ---- BiAMLP (txt|aud merged, fp32-A LDS path) ----
    OpDesc dTxt = {}, dAud = {};
    dTxt.A = (const unsigned short*)txt; dTxt.lda = 128;
    dTxt.B0 = WiTb; dTxt.ldb = 128;
    dTxt.C = q1b; dTxt.ldc = 128;
    dTxt.E0 = bi; dTxt.ss = partial; dTxt.Kd = 128;
    dAud = dTxt;
    dAud.A = (const unsigned short*)aud; dAud.B0 = WqTb; dAud.C = q2b;
    dAud.E0 = bq; dAud.ss = partial + 1024;
    mg<4, 4, 1, 0, 128><<<dim3(512, 2, 2), 256, 0, stream>>>(dTxt, dAud, 1);

    k2z<<<dim3(64, 16), 256, 0, stream>>>(q1b, q2b, partial, colssP);
    k3nT<<<dim3(64, 8), 256, 0, stream>>>(q1b, colssP, GT);

    // ---- S2 || U merged (shared A = featT): grid (1, 8+2, 192) ----
    OpDesc dS2 = {};
    dS2.A = featT; dS2.aOff0 = 0; dS2.aOff1 = BLD_; dS2.aOff2 = 2 * BLD_;
    dS2.sA = LD_; dS2.lda = 1024;
    dS2.B0 = WAb; dS2.bOff0 = 0; dS2.bOff1 = 1048576; dS2.bOff2 = 2097152;
    dS2.sB0 = 0; dS2.ldb = 1024;
    dS2.C = S2all; dS2.sC = LD_; dS2.ldc = 1024; dS2.Kd = 1024;
    OpDesc dU = {};
    dU.A = featT; dU.aOff0 = 0; dU.aOff1 = BLD_; dU.aOff2 = 2 * BLD_;
    dU.sA = LD_; dU.lda = 1024;
    dU.B0 = WLTb; dU.bOff0 = 0; dU.bOff1 = 262144; dU.bOff2 = 524288;
    dU.sB0 = 0; dU.ldb = 1024;
    dU.C = Hb3; dU.sC = 32768; dU.ldc = 256; dU.Kd = 1024;
    mgy<0, 0, 1, 128><<<dim3(1, 10, 192), 256, 0, stream>>>(dS2, dU, 8);

    // ---- att (tanh) standalone: 64-row tiles ----
    OpDesc dAtt = {};
    dAtt.A = S2all; dAtt.aOff0 = 0; dAtt.aOff1 = 64 * LD_; dAtt.aOff2 = 128 * LD_;
    dAtt.sA = LD_; dAtt.lda = 1024;
    dAtt.B0 = featT; dAtt.bOff0 = 0; dAtt.bOff1 = 0; dAtt.bOff2 = 2 * BLD_;  // audT,audT,txtT
    dAtt.sB0 = LD_;
    dAtt.B1 = GT; dAtt.sB1 = LD_; dAtt.ldb = 1024;
    dAtt.C = Cm3; dAtt.sC = 32768; dAtt.ldc = 256; dAtt.Kd = 1024;
    mg<1, 1, 0, 1, 64><<<dim3(2, 2, 192), 256, 0, stream>>>(dAtt, dAtt, 192);

    // ---- T: Hb = relu(Cm @ WC + Hb): 64-row tiles ----
    OpDesc dT = {};
    dT.A = Cm3; dT.aOff0 = 0; dT.aOff1 = 2097152; dT.aOff2 = 4194304;
    dT.sA = 32768; dT.lda = 256;
    dT.B0 = WCTb; dT.bOff0 = 0; dT.bOff1 = 65536; dT.bOff2 = 131072;
    dT.sB0 = 0; dT.ldb = 256;
    dT.C = Hb3; dT.sC = 32768; dT.ldc = 256; dT.Kd = 256;
    mg<2, 2, 0, 1, 64><<<dim3(2, 2, 192), 256, 0, stream>>>(dT, dT, 192);

    // ---- out: out[b,l,d] = WH^T @ Hb^T + residual ----
    OpDesc dOut = {};
    dOut.A = WHTb; dOut.aOff0 = 0; dOut.aOff1 = 262144; dOut.aOff2 = 524288;
    dOut.sA = 0; dOut.lda = 256;
    dOut.B0 = Hb3; dOut.bOff0 = 0; dOut.bOff1 = 2097152; dOut.bOff2 = 4194304;
    dOut.sB0 = 32768; dOut.ldb = 256;
    dOut.C = d_out; dOut.ldc = 128;
    dOut.E0 = aud; dOut.E1 = vis; dOut.E2 = txt; dOut.Kd = 256;
    mg<3, 3, 0, 1, 128><<<dim3(8, 1, 192), 256, 0, stream>>>(dOut, dOut, 192);
}

// Round 16
// 286.677 us; speedup vs baseline: 1.2370x; 1.0148x over previous
//
#include <hip/hip_runtime.h>
#include <math.h>

typedef __attribute__((ext_vector_type(8))) short bf16x8;
typedef __attribute__((ext_vector_type(4))) float f32x4;

static constexpr int B_ = 64, L_ = 1024, D_ = 128, K_ = 256;
static constexpr long BLD_ = (long)B_ * L_ * D_;      // 8,388,608
static constexpr long LD_  = (long)L_ * D_;           // 131,072

__device__ __forceinline__ unsigned short f2b(float f) {
    unsigned int u = __builtin_bit_cast(unsigned int, f);
    u = (u + 0x7fffu + ((u >> 16) & 1u)) >> 16;
    return (unsigned short)u;
}
__device__ __forceinline__ float b2f(unsigned short h) {
    unsigned int u = ((unsigned int)h) << 16;
    return __builtin_bit_cast(float, u);
}

__device__ __forceinline__ void gl16(const unsigned short* g, unsigned short* s) {
    __builtin_amdgcn_global_load_lds(
        (const __attribute__((address_space(1))) unsigned int*)g,
        (__attribute__((address_space(3))) unsigned int*)s, 16, 0, 0);
}

// ---- fused transpose/convert: fp32 [R][C] -> bf16 [C][R] (tr=1) or [R][C] (tr=0) ----
struct TrEnt { const float* src; unsigned short* dst; int R, C, tr, start; };
struct TrTab { TrEnt e[17]; };

__device__ __forceinline__ void tr_body(const TrEnt& e, int tile, int t,
                                        unsigned short (*T)[72])
{
    int ntR = e.R >> 6, ntC = e.C >> 6;
    int nt = ntR * ntC;
    int bb = tile / nt, tt = tile - bb * nt;
    int ri = tt % ntR, ci = tt / ntR;
    const float* src = e.src + (long)bb * e.R * e.C + (long)(ri * 64) * e.C + ci * 64;
    if (!e.tr) {
        unsigned short* dstd = e.dst + (long)bb * e.R * e.C + (long)(ri * 64) * e.C + ci * 64;
        int r = t >> 2, cq = t & 3;
        const float* s = src + (long)r * e.C + cq * 16;
        unsigned short tmp[16];
        #pragma unroll
        for (int f = 0; f < 4; ++f) {
            float4 v = *(const float4*)(s + f * 4);
            tmp[f*4+0]=f2b(v.x); tmp[f*4+1]=f2b(v.y); tmp[f*4+2]=f2b(v.z); tmp[f*4+3]=f2b(v.w);
        }
        unsigned short* dp = dstd + (long)r * e.C + cq * 16;
        *(uint4*)&dp[0] = *(uint4*)&tmp[0];
        *(uint4*)&dp[8] = *(uint4*)&tmp[8];
        return;
    }
    unsigned short* dst = e.dst + (long)bb * e.R * e.C + (long)(ci * 64) * e.R + ri * 64;
    {
        int r = t >> 2, cq = t & 3;
        const float* s = src + (long)r * e.C + cq * 16;
        unsigned short tmp[16];
        #pragma unroll
        for (int f = 0; f < 4; ++f) {
            float4 v = *(const float4*)(s + f * 4);
            tmp[f*4+0]=f2b(v.x); tmp[f*4+1]=f2b(v.y); tmp[f*4+2]=f2b(v.z); tmp[f*4+3]=f2b(v.w);
        }
        *(uint4*)&T[r][cq*16]   = *(uint4*)&tmp[0];
        *(uint4*)&T[r][cq*16+8] = *(uint4*)&tmp[8];
    }
    __syncthreads();
    {
        int cr = t >> 2, rq = t & 3;
        unsigned short tmp[16];
        #pragma unroll
        for (int j = 0; j < 16; ++j) tmp[j] = T[rq*16 + j][cr];
        unsigned short* dp = dst + (long)cr * e.R + rq * 16;
        *(uint4*)&dp[0] = *(uint4*)&tmp[0];
        *(uint4*)&dp[8] = *(uint4*)&tmp[8];
    }
}

__global__ __launch_bounds__(256)
void trk(TrTab tab)
{
    __shared__ unsigned short T[64][72];
    int bid = blockIdx.x;
    int ei = 0;
    #pragma unroll
    for (int i = 1; i < 17; ++i) if (bid >= tab.e[i].start) ei = i;
    TrEnt e = tab.e[ei];
    tr_body(e, bid - e.start, threadIdx.x, T);
}

// ---------------- unified MFMA GEMM ----------------
struct OpDesc {
    const unsigned short* A;
    long aOff0, aOff1, aOff2, sA;
    int lda;
    const unsigned short* B0;
    long bOff0, bOff1, bOff2, sB0;
    const unsigned short* B1;
    long sB1;
    int ldb;
    void* C;
    long sC;
    int ldc;
    const float* E0; const float* E1; const float* E2;
    float* ss;
    int Kd;
};

// LDS chunk swizzle: LDS(row, ch) holds global chunk ch ^ ((row>>1)&3).
// gl16: linear dest; per-lane SOURCE chunk = (l&3)^((l>>3)&3). Read: rc = (kg^((fr>>1)&3))*8.
// EPI: 0 store bf16; 1 tanh(acc/16)->bf16; 2 relu(acc+C_old)->bf16 inplace;
//      3 fp32 out + residual; 4 bias+pool->bf16 + per-block sumsq partial
template<int EPI, int AF32, int TM>
__device__ __forceinline__ void gbody(const OpDesc& d, int bx, int by, int zrem,
                                      unsigned short (*As)[TM][32],
                                      unsigned short (*Bs)[128][32])
{
    const int tid = threadIdx.x;
    const long m0 = (long)bx * TM;
    const int n0 = by * 128;
    const int br = zrem >> 6, bb = zrem & 63;

    long aO = (br == 0 ? d.aOff0 : br == 1 ? d.aOff1 : d.aOff2) + (long)bb * d.sA;
    const unsigned short* A_ = d.A + aO;
    const float* Af = (const float*)d.A;
    const unsigned short* Bp;
    int nB = n0;
    if (d.B1 && n0 >= 128) { Bp = d.B1 + (long)bb * d.sB1; nB = n0 - 128; }
    else { Bp = d.B0 + (br == 0 ? d.bOff0 : br == 1 ? d.bOff1 : d.bOff2) + (long)bb * d.sB0; }

    const int w = tid >> 6, l = tid & 63;
    const int wm = (TM == 128) ? (w >> 1) : 0;
    const int wn = (TM == 128) ? (w & 1) : w;
    const int NJ = (TM == 128) ? 4 : 2;
    const int WS = (TM == 128) ? 64 : 32;
    const int fr = l & 15, kg = l >> 4;

    f32x4 acc[4][4];
    #pragma unroll
    for (int i = 0; i < 4; ++i)
        #pragma unroll
        for (int j = 0; j < 4; ++j)
            acc[i][j] = (f32x4){0.f, 0.f, 0.f, 0.f};

    const int sc8 = ((l & 3) ^ ((l >> 3) & 3)) * 8;   // swizzled source chunk offset
    const int rc  = (kg ^ ((fr >> 1) & 3)) * 8;        // swizzled read col

    auto stage = [&](int buf, int k0) {
        if (AF32) {
            int row = tid >> 1, half = tid & 1;
            const float* s = Af + (long)(m0 + row) * d.lda + k0 + half * 16;
            unsigned short tmp[16];
            #pragma unroll
            for (int f = 0; f < 4; ++f) {
                float4 v = *(const float4*)(s + f * 4);
                tmp[f*4+0]=f2b(v.x); tmp[f*4+1]=f2b(v.y); tmp[f*4+2]=f2b(v.z); tmp[f*4+3]=f2b(v.w);
            }
            int sw = (row >> 1) & 3;
            *(uint4*)&As[buf][row][((2*half    ) ^ sw) * 8] = *(uint4*)&tmp[0];
            *(uint4*)&As[buf][row][((2*half + 1) ^ sw) * 8] = *(uint4*)&tmp[8];
        } else if (TM == 128) {
            const unsigned short* ga = A_ + (m0 + 32*w + (l >> 2)) * (long)d.lda + k0 + sc8;
            gl16(ga,                    &As[buf][32*w][0]);
            gl16(ga + 16*(long)d.lda,   &As[buf][32*w + 16][0]);
        } else {
            const unsigned short* ga = A_ + (m0 + 16*w + (l >> 2)) * (long)d.lda + k0 + sc8;
            gl16(ga, &As[buf][16*w][0]);
        }
        const unsigned short* gb = Bp + (long)(nB + 32*w + (l >> 2)) * d.ldb + k0 + sc8;
        gl16(gb,                  &Bs[buf][32*w][0]);
        gl16(gb + 16*(long)d.ldb, &Bs[buf][32*w + 16][0]);
    };

    auto compute = [&](int cb) {
        bf16x8 af[4], bf[4];
        #pragma unroll
        for (int i = 0; i < 4; ++i) af[i] = *(const bf16x8*)&As[cb][wm*64 + i*16 + fr][rc];
        #pragma unroll
        for (int j = 0; j < NJ; ++j) bf[j] = *(const bf16x8*)&Bs[cb][wn*WS + j*16 + fr][rc];
        #pragma unroll
        for (int i = 0; i < 4; ++i)
            #pragma unroll
            for (int j = 0; j < NJ; ++j)
                acc[i][j] = __builtin_amdgcn_mfma_f32_16x16x32_bf16(af[i], bf[j], acc[i][j], 0, 0, 0);
    };

    const int nt = d.Kd >> 5;
    stage(0, 0);
    __syncthreads();
    for (int t = 0; t < nt; ++t) {
        if (t + 1 < nt) stage((t + 1) & 1, (t + 1) << 5);
        compute(t & 1);
        __syncthreads();
    }

    if (EPI == 4) {
        unsigned short* C = (unsigned short*)d.C;
        float lss = 0.f;
        #pragma unroll
        for (int i = 0; i < 4; ++i)
            #pragma unroll
            for (int j = 0; j < 4; ++j) {
                int cg = n0 + wn*64 + j*16 + fr;
                float bias = d.E0[cg];
                #pragma unroll
                for (int r = 0; r < 4; ++r) {
                    float v = acc[i][j][r] + bias;
                    lss += v * v;
                }
            }
        #pragma unroll
        for (int o = 32; o; o >>= 1) lss += __shfl_xor(lss, o);
        __shared__ float red4[4];
        if (l == 0) red4[w] = lss;
        float* eb = (float*)As;
        #pragma unroll
        for (int cc = 0; cc < 4; ++cc) {
            __syncthreads();
            #pragma unroll
            for (int j = 0; j < 4; ++j) {
                int cg = n0 + wn*64 + j*16 + fr;
                float bias = d.E0[cg];
                #pragma unroll
                for (int r = 0; r < 4; ++r)
                    eb[(wm*16 + kg*4 + r)*128 + wn*64 + j*16 + fr] = acc[cc][j][r] + bias;
            }
            __syncthreads();
            int lr = tid >> 3, pc = tid & 7;
            long gr = m0 + (lr < 16 ? cc*16 + lr : 48 + cc*16 + lr);
            unsigned short pk[8];
            #pragma unroll
            for (int e = 0; e < 8; ++e) {
                float v0 = eb[lr*128 + pc*16 + 2*e];
                float v1 = eb[lr*128 + pc*16 + 2*e + 1];
                pk[e] = f2b(v0 + v1);
            }
            *(uint4*)&C[gr * (long)d.ldc + (n0 >> 1) + pc*8] = *(uint4*)&pk[0];
        }
        if (tid == 0)
            d.ss[bx * 2 + by] = red4[0] + red4[1] + red4[2] + red4[3];
    } else if (TM == 64) {
        float* eb = (float*)As;
        #pragma unroll
        for (int cc = 0; cc < 4; ++cc) {
            __syncthreads();
            #pragma unroll
            for (int j = 0; j < 2; ++j)
                #pragma unroll
                for (int r = 0; r < 4; ++r)
                    eb[(kg*4 + r)*128 + wn*32 + j*16 + fr] = acc[cc][j][r];
            __syncthreads();
            unsigned short* C = (unsigned short*)d.C + (long)zrem * d.sC;
            int colx = (tid & 15) * 8;
            int lr = tid >> 4;
            long gr = m0 + cc*16 + lr;
            long gi = gr * (long)d.ldc + n0 + colx;
            unsigned short ov[8];
            if (EPI == 2) *(uint4*)ov = *(const uint4*)&C[gi];
            unsigned short pk[8];
            #pragma unroll
            for (int e = 0; e < 8; ++e) {
                float v = eb[lr*128 + colx + e];
                if (EPI == 1) v = tanhf(v * 0.0625f);
                if (EPI == 2) v = fmaxf(v + b2f(ov[e]), 0.f);
                pk[e] = f2b(v);
            }
            *(uint4*)&C[gi] = *(uint4*)&pk[0];
        }
    } else {
        float* eb = (float*)As;
        #pragma unroll
        for (int cc = 0; cc < 4; ++cc) {
            __syncthreads();
            #pragma unroll
            for (int j = 0; j < 4; ++j)
                #pragma unroll
                for (int r = 0; r < 4; ++r)
                    eb[(wm*16 + kg*4 + r)*128 + wn*64 + j*16 + fr] = acc[cc][j][r];
            __syncthreads();
            if (EPI == 3) {
                long off = (br == 2) ? 0L : (long)(br + 1) * BLD_;
                float* Co = (float*)d.C + off + (long)bb * LD_;
                const float* Ep = (br == 0 ? d.E0 : br == 1 ? d.E1 : d.E2) + (long)bb * LD_;
                int colx = (tid & 31) * 4;
                #pragma unroll
                for (int p = 0; p < 4; ++p) {
                    int lr = (tid >> 5) + 8 * p;
                    long gr = m0 + (lr < 16 ? cc*16 + lr : 48 + cc*16 + lr);
                    long gi = gr * (long)d.ldc + n0 + colx;
                    float4 v = *(float4*)&eb[lr*128 + colx];
                    float4 e4 = *(const float4*)&Ep[gi];
                    v.x += e4.x; v.y += e4.y; v.z += e4.z; v.w += e4.w;
                    *(float4*)&Co[gi] = v;
                }
            } else {
                unsigned short* C = (unsigned short*)d.C + (long)zrem * d.sC;
                int colx = (tid & 15) * 8;
                #pragma unroll
                for (int p = 0; p < 2; ++p) {
                    int lr = (tid >> 4) + 16 * p;
                    long gr = m0 + (lr < 16 ? cc*16 + lr : 48 + cc*16 + lr);
                    long gi = gr * (long)d.ldc + n0 + colx;
                    unsigned short ov[8];
                    if (EPI == 2) *(uint4*)ov = *(const uint4*)&C[gi];
                    unsigned short pk[8];
                    #pragma unroll
                    for (int e = 0; e < 8; ++e) {
                        float v = eb[lr*128 + colx + e];
                        if (EPI == 1) v = tanhf(v * 0.0625f);
                        if (EPI == 2) v = fmaxf(v + b2f(ov[e]), 0.f);
                        pk[e] = f2b(v);
                    }
                    *(uint4*)&C[gi] = *(uint4*)&pk[0];
                }
            }
        }
    }
}

// SWZ=1: XCD-aware bijective remap (requires nwg % 8 == 0); split on z
template<int EPI0, int EPI1, int AF32, int SWZ, int TM>
__global__ __launch_bounds__(256)
void mg(OpDesc d0, OpDesc d1, int zsplit)
{
    __shared__ __align__(16) unsigned short As[2][TM][32];
    __shared__ __align__(16) unsigned short Bs[2][128][32];
    int bx, by, bz;
    if (SWZ) {
        int nwg = gridDim.x * gridDim.y * gridDim.z;
        int c = blockIdx.x + gridDim.x * (blockIdx.y + gridDim.y * blockIdx.z);
        int lid = (c & 7) * (nwg >> 3) + (c >> 3);
        bx = lid % gridDim.x; lid /= gridDim.x;
        by = lid % gridDim.y; bz = lid / gridDim.y;
    } else {
        bx = blockIdx.x; by = blockIdx.y; bz = blockIdx.z;
    }
    if (bz < zsplit) gbody<EPI0, AF32, TM>(d0, bx, by, bz, As, Bs);
    else             gbody<EPI1, AF32, TM>(d1, bx, by, bz - zsplit, As, Bs);
}

// split on y: by<ysplit -> d0, else d1 with by-=ysplit (shared-A merge: S2 || U)
template<int EPI0, int EPI1, int SWZ, int TM>
__global__ __launch_bounds__(256)
void mgy(OpDesc d0, OpDesc d1, int ysplit)
{
    __shared__ __align__(16) unsigned short As[2][TM][32];
    __shared__ __align__(16) unsigned short Bs[2][128][32];
    int bx, by, bz;
    if (SWZ) {
        int nwg = gridDim.x * gridDim.y * gridDim.z;
        int c = blockIdx.x + gridDim.x * (blockIdx.y + gridDim.y * blockIdx.z);
        int lid = (c & 7) * (nwg >> 3) + (c >> 3);
        bx = lid % gridDim.x; lid /= gridDim.x;
        by = lid % gridDim.y; bz = lid / gridDim.y;
    } else {
        bx = blockIdx.x; by = blockIdx.y; bz = blockIdx.z;
    }
    if (by < ysplit) gbody<EPI0, 0, TM>(d0, bx, by, bz, As, Bs);
    else             gbody<EPI1, 0, TM>(d1, bx, by - ysplit, bz, As, Bs);
}

// merged: feat transposes (6144 blocks) || BiAMLP (2048 blocks)
__global__ __launch_bounds__(256)
void mgbi(TrEnt e0, TrEnt e1, TrEnt e2, OpDesc dTxt, OpDesc dAud)
{
    __shared__ __align__(16) unsigned short As[2][128][32];
    __shared__ __align__(16) unsigned short Bs[2][128][32];
    int bid = blockIdx.x;
    if (bid < 6144) {
        TrEnt e = (bid < 2048) ? e0 : (bid < 4096) ? e1 : e2;
        tr_body(e, bid & 2047, threadIdx.x, (unsigned short (*)[72])As);
    } else {
        int rem = bid - 6144;
        int z = rem >> 10;
        int t = rem & 1023;
        gbody<4, 1, 128>(z ? dAud : dTxt, t >> 1, t & 1, 0, As, Bs);
    }
}

// z = al*q1 + be*q2 (bf16 in place on q1) + per-(b,lc) column sumsq partials (no atomics)
__global__ __launch_bounds__(256)
void k2z(unsigned short* __restrict__ q1, const unsigned short* __restrict__ q2,
         const float* __restrict__ partial, float* __restrict__ colssP)
{
    int t = threadIdx.x;
    float a = partial[t] + partial[t + 256] + partial[t + 512] + partial[t + 768];
    float bsum = partial[1024 + t] + partial[1280 + t] + partial[1536 + t] + partial[1792 + t];
    #pragma unroll
    for (int o = 32; o; o >>= 1) { a += __shfl_xor(a, o); bsum += __shfl_xor(bsum, o); }
    __shared__ float ra[4], rb[4];
    int wv = t >> 6;
    if ((t & 63) == 0) { ra[wv] = a; rb[wv] = bsum; }
    __syncthreads();
    float n1 = sqrtf(ra[0] + ra[1] + ra[2] + ra[3]);
    float n2 = sqrtf(rb[0] + rb[1] + rb[2] + rb[3]);
    float al = n1 / (n1 + n2), be = n2 / (n1 + n2);

    int b = blockIdx.x, lc = blockIdx.y;
    int d = t & 127, ls = t >> 7;
    long base = ((long)b * L_ + (long)lc * 64) * D_;
    float acc = 0.f;
    for (int ll = ls; ll < 64; ll += 2) {
        long idx = base + (long)ll * D_ + d;
        float zv = al * b2f(q1[idx]) + be * b2f(q2[idx]);
        q1[idx] = f2b(zv);
        acc += zv * zv;
    }
    __shared__ float red[256];
    red[t] = acc;
    __syncthreads();
    if (t < 128)
        colssP[((long)b * 16 + lc) * 128 + d] = red[t] + red[t + 128];
}

// GT[b][d][l] = z[b][l][d] / max(sqrt(sum_lc colssP[b][lc][d]),1e-12)
__global__ __launch_bounds__(256)
void k3nT(const unsigned short* __restrict__ z, const float* __restrict__ colssP,
          unsigned short* __restrict__ GT)
{
    __shared__ unsigned short T[128][136];
    int b = blockIdx.x, lt = blockIdx.y;
    int t = threadIdx.x;
    {
        int r = t >> 1, half = t & 1;
        const unsigned short* src = z + ((long)b * L_ + lt * 128 + r) * D_ + half * 64;
        #pragma unroll
        for (int q = 0; q < 8; ++q)
            *(uint4*)&T[r][half*64 + q*8] = *(const uint4*)(src + q*8);
    }
    __syncthreads();
    {
        int d = t >> 1, lh = t & 1;
        float s = 0.f;
        #pragma unroll
        for (int lc = 0; lc < 16; ++lc)
            s += colssP[((long)b * 16 + lc) * 128 + d];
        float inv = 1.f / fmaxf(sqrtf(s), 1e-12f);
        unsigned short tmp[64];
        #pragma unroll
        for (int j = 0; j < 64; ++j) tmp[j] = f2b(b2f(T[lh*64 + j][d]) * inv);
        unsigned short* dp = GT + ((long)b * D_ + d) * L_ + lt * 128 + lh * 64;
        #pragma unroll
        for (int q = 0; q < 8; ++q) *(uint4*)&dp[q*8] = *(uint4*)&tmp[q*8];
    }
}

extern "C" void kernel_launch(void* const* d_in, const int* in_sizes, int n_in,
                              void* d_out, int out_size, void* d_ws, size_t ws_size,
                              hipStream_t stream)
{
    const float* txt = (const float*)d_in[0];
    const float* aud = (const float*)d_in[1];
    const float* vis = (const float*)d_in[2];
    const float* Wi  = (const float*)d_in[3];
    const float* bi  = (const float*)d_in[4];
    const float* Wq  = (const float*)d_in[5];
    const float* bq  = (const float*)d_in[6];
    const float* Waff[3] = { (const float*)d_in[7], (const float*)d_in[8], (const float*)d_in[9] };
    const float* Wlin[3] = { (const float*)d_in[10], (const float*)d_in[11], (const float*)d_in[12] };
    const float* Wc[3]   = { (const float*)d_in[13], (const float*)d_in[14], (const float*)d_in[15] };
    const float* Wh[3]   = { (const float*)d_in[16], (const float*)d_in[17], (const float*)d_in[18] };

    // ---- workspace (bf16 elems) ----
    unsigned short* w16 = (unsigned short*)d_ws;
    unsigned short* featT = w16;                      // 3*BLD  [aud,vis,txt] x [b][d][l]
    unsigned short* q1b   = featT + 3 * BLD_;         // 8,388,608
    unsigned short* q2b   = q1b + BLD_;               // 8,388,608
    unsigned short* WAb   = q2b + BLD_;               // 3,145,728
    unsigned short* WLTb  = WAb + 3145728;            // 786,432
    unsigned short* WCTb  = WLTb + 786432;            // 196,608
    unsigned short* WHTb  = WCTb + 196608;            // 786,432
    unsigned short* WiTb  = WHTb + 786432;            // 32,768
    unsigned short* WqTb  = WiTb + 32768;             // 32,768
    float* partial = (float*)(WqTb + 32768);          // 2048 block partials
    float* colssP  = partial + 2048;                  // 131,072 partials
    // overlays (q1/q2 dead after k3nT)
    unsigned short* Cm3 = q1b;                        // 6,291,456
    unsigned short* Hb3 = q1b + 6291456;              // 6,291,456
    // d_out scratch (fully overwritten by final GEMM)
    unsigned short* S2all = (unsigned short*)d_out;   // 25,165,824
    unsigned short* GT    = S2all + 3 * BLD_;         // 8,388,608

    // ---- phase 1: weight conversions only ----
    TrTab tab;
    auto setE = [&](int i, const float* s, unsigned short* dst, int R, int C, int tr, int start) {
        tab.e[i].src = s; tab.e[i].dst = dst; tab.e[i].R = R; tab.e[i].C = C;
        tab.e[i].tr = tr; tab.e[i].start = start;
    };
    int st = 0;
    setE(0, Wi, WiTb, 128, 256, 1, st); st += 8;
    setE(1, Wq, WqTb, 128, 256, 1, st); st += 8;
    for (int i = 0; i < 3; ++i) { setE(2 + i, Wlin[i], WLTb + (long)i * 262144, 1024, 256, 1, st); st += 64; }
    for (int i = 0; i < 3; ++i) { setE(5 + i, Wc[i],   WCTb + (long)i * 65536,  256, 256, 1, st); st += 16; }
    for (int i = 0; i < 3; ++i) { setE(8 + i, Wh[i],   WHTb + (long)i * 262144, 256, 1024, 1, st); st += 64; }
    for (int i = 0; i < 3; ++i) { setE(11 + i, Waff[i], WAb + (long)i * 1048576, 1024, 1024, 0, st); st += 256; }
    for (int i = 14; i < 17; ++i) { tab.e[i].start = 1 << 30; tab.e[i].src = nullptr; }
    trk<<<st, 256, 0, stream>>>(tab);

    // ---- phase 2: feat transposes || BiAMLP (merged) ----
    TrEnt eA = { aud, featT + 0,        1024, 128, 1, 0 };
    TrEnt eV = { vis, featT + BLD_,     1024, 128, 1, 0 };
    TrEnt eT = { txt, featT + 2 * BLD_, 1024, 128, 1, 0 };
    OpDesc dTxt = {}, dAud = {};
    dTxt.A = (const unsigned short*)txt; dTxt.lda = 128;
    dTxt.B0 = WiTb; dTxt.ldb = 128;
    dTxt.C = q1b; dTxt.ldc = 128;
    dTxt.E0 = bi; dTxt.ss = partial; dTxt.Kd = 128;
    dAud = dTxt;
    dAud.A = (const unsigned short*)aud; dAud.B0 = WqTb; dAud.C = q2b;
    dAud.E0 = bq; dAud.ss = partial + 1024;
    mgbi<<<8192, 256, 0, stream>>>(eA, eV, eT, dTxt, dAud);

    k2z<<<dim3(64, 16), 256, 0, stream>>>(q1b, q2b, partial, colssP);
    k3nT<<<dim3(64, 8), 256, 0, stream>>>(q1b, colssP, GT);

    // ---- S2 || U merged (shared A = featT): grid (1, 8+2, 192) ----
    OpDesc dS2 = {};
    dS2.A = featT; dS2.aOff0 = 0; dS2.aOff1 = BLD_; dS2.aOff2 = 2 * BLD_;
    dS2.sA = LD_; dS2.lda = 1024;
    dS2.B0 = WAb; dS2.bOff0 = 0; dS2.bOff1 = 1048576; dS2.bOff2 = 2097152;
    dS2.sB0 = 0; dS2.ldb = 1024;
    dS2.C = S2all; dS2.sC = LD_; dS2.ldc = 1024; dS2.Kd = 1024;
    OpDesc dU = {};
    dU.A = featT; dU.aOff0 = 0; dU.aOff1 = BLD_; dU.aOff2 = 2 * BLD_;
    dU.sA = LD_; dU.lda = 1024;
    dU.B0 = WLTb; dU.bOff0 = 0; dU.bOff1 = 262144; dU.bOff2 = 524288;
    dU.sB0 = 0; dU.ldb = 1024;
    dU.C = Hb3; dU.sC = 32768; dU.ldc = 256; dU.Kd = 1024;
    mgy<0, 0, 1, 128><<<dim3(1, 10, 192), 256, 0, stream>>>(dS2, dU, 8);

    // ---- att (tanh) standalone: 64-row tiles ----
    OpDesc dAtt = {};
    dAtt.A = S2all; dAtt.aOff0 = 0; dAtt.aOff1 = 64 * LD_; dAtt.aOff2 = 128 * LD_;
    dAtt.sA = LD_; dAtt.lda = 1024;
    dAtt.B0 = featT; dAtt.bOff0 = 0; dAtt.bOff1 = 0; dAtt.bOff2 = 2 * BLD_;  // audT,audT,txtT
    dAtt.sB0 = LD_;
    dAtt.B1 = GT; dAtt.sB1 = LD_; dAtt.ldb = 1024;
    dAtt.C = Cm3; dAtt.sC = 32768; dAtt.ldc = 256; dAtt.Kd = 1024;
    mg<1, 1, 0, 1, 64><<<dim3(2, 2, 192), 256, 0, stream>>>(dAtt, dAtt, 192);

    // ---- T: Hb = relu(Cm @ WC + Hb): 64-row tiles ----
    OpDesc dT = {};
    dT.A = Cm3; dT.aOff0 = 0; dT.aOff1 = 2097152; dT.aOff2 = 4194304;
    dT.sA = 32768; dT.lda = 256;
    dT.B0 = WCTb; dT.bOff0 = 0; dT.bOff1 = 65536; dT.bOff2 = 131072;
    dT.sB0 = 0; dT.ldb = 256;
    dT.C = Hb3; dT.sC = 32768; dT.ldc = 256; dT.Kd = 256;
    mg<2, 2, 0, 1, 64><<<dim3(2, 2, 192), 256, 0, stream>>>(dT, dT, 192);

    // ---- out: out[b,l,d] = WH^T @ Hb^T + residual ----
    OpDesc dOut = {};
    dOut.A = WHTb; dOut.aOff0 = 0; dOut.aOff1 = 262144; dOut.aOff2 = 524288;
    dOut.sA = 0; dOut.lda = 256;
    dOut.B0 = Hb3; dOut.bOff0 = 0; dOut.bOff1 = 2097152; dOut.bOff2 = 4194304;
    dOut.sB0 = 32768; dOut.ldb = 256;
    dOut.C = d_out; dOut.ldc = 128;
    dOut.E0 = aud; dOut.E1 = vis; dOut.E2 = txt; dOut.Kd = 256;
    mg<3, 3, 0, 1, 128><<<dim3(8, 1, 192), 256, 0, stream>>>(dOut, dOut, 192);
}